// Round 10
// baseline (628.499 us; speedup 1.0000x reference)
//
#include <hip/hip_runtime.h>
#include <cstdint>
#include <cstddef>

typedef short    bf16x8 __attribute__((ext_vector_type(8)));
typedef _Float16 f16x8  __attribute__((ext_vector_type(8)));
typedef _Float16 f16x4  __attribute__((ext_vector_type(4)));
typedef float    f32x4  __attribute__((ext_vector_type(4)));

#define NEGV (-1e30f)
#define LDT 40   // padded LDS row pitch (shorts) = 80B: 16B-aligned, 2-way-conflict max (free)

__device__ __forceinline__ short f2bf(float x){
    union { float f; unsigned u; } v; v.f = x;
    return (short)((v.u + 0x7fffu + ((v.u >> 16) & 1u)) >> 16);
}
__device__ __forceinline__ float bf2f(short h){
    union { float f; unsigned u; } v; v.u = ((unsigned)(unsigned short)h) << 16; return v.f;
}
__device__ __forceinline__ short f2h(float x){
    _Float16 h = (_Float16)x;
    union { _Float16 h; unsigned short u; } v; v.h = h;
    return (short)v.u;
}
__device__ __forceinline__ unsigned packh(float a, float b){
    return (unsigned)(unsigned short)f2h(a) | ((unsigned)(unsigned short)f2h(b) << 16);
}
// memory row (within a 64-row group) holding logical column h:
// epi's B-fragment load at row ni*16+fr then yields logical col fr*4+ni (consecutive per thread)
__device__ __forceinline__ int p64(int x){ return ((x & 3) << 4) | (x >> 2); }

// ---------------- prep: W1,W2 -> transposed bf16 hi/lo (MLP stays split-bf16) ----------------
__global__ __launch_bounds__(256)
void k_prep_w(const float* __restrict__ W1, const float* __restrict__ W2,
              short* __restrict__ W1Th, short* __restrict__ W1Tl,
              short* __restrict__ W2Th, short* __restrict__ W2Tl)
{
    int idx = blockIdx.x * 256 + threadIdx.x;
    int w = idx >> 18;
    int e = idx & ((1 << 18) - 1);
    int n = e & 511, k = e >> 9;
    const float* W = w ? W2 : W1;
    float x = W[k * 512 + n];
    short hi = f2bf(x);
    short lo = f2bf(x - bf2f(hi));
    size_t o = (size_t)n * 512 + k;
    if (w) { W2Th[o] = hi; W2Tl[o] = lo; } else { W1Th[o] = hi; W1Tl[o] = lo; }
}

// ---------------- prep q: qT (fp16, transposed, h-permuted), q_cq = f16(q*cqw), s1 partials ----------------
__global__ __launch_bounds__(256)
void k_prep_q(const float* __restrict__ q, const float* __restrict__ qwv,
              const float* __restrict__ cqw, short* __restrict__ q_cq,
              short* __restrict__ qT, float* __restrict__ s1p)
{
    __shared__ short TT[128 * 136];
    __shared__ float qws[128], cqs[128];
    const int t = threadIdx.x;
    const int b = (int)(blockIdx.x >> 2), hb = (int)(blockIdx.x & 3), h0 = hb * 128;
    if (t < 128) { qws[t] = qwv[h0 + t]; cqs[t] = cqw[h0 + t]; }
    __syncthreads();
    #pragma unroll
    for (int it = 0; it < 16; it++) {
        int idx = it * 256 + t;
        int m = idx >> 5, c4 = (idx & 31) * 4;
        float4 v = *(const float4*)(q + ((size_t)b * 128 + m) * 512 + h0 + c4);
        TT[(c4 + 0) * 136 + m] = f2h(v.x);
        TT[(c4 + 1) * 136 + m] = f2h(v.y);
        TT[(c4 + 2) * 136 + m] = f2h(v.z);
        TT[(c4 + 3) * 136 + m] = f2h(v.w);
        uint2 d;
        d.x = packh(v.x * cqs[c4],     v.y * cqs[c4 + 1]);
        d.y = packh(v.z * cqs[c4 + 2], v.w * cqs[c4 + 3]);
        *(uint2*)(q_cq + ((size_t)b * 128 + m) * 512 + h0 + c4) = d;
        float dot = v.x * qws[c4] + v.y * qws[c4 + 1] + v.z * qws[c4 + 2] + v.w * qws[c4 + 3];
        #pragma unroll
        for (int off = 1; off < 32; off <<= 1) dot += __shfl_xor(dot, off);
        if ((t & 31) == 0) s1p[((size_t)b * 4 + hb) * 128 + m] = dot;
    }
    __syncthreads();
    const int h = t >> 1, half = t & 1;
    const int hm = (h & 64) + p64(h & 63);   // permuted destination row
    short* dst = qT + ((size_t)b * 512 + h0 + hm) * 128 + half * 64;
    #pragma unroll
    for (int j = 0; j < 8; j++)
        *(bf16x8*)(dst + j * 8) = *(const bf16x8*)&TT[h * 136 + half * 64 + j * 8];
}

// ---------------- split-bf16 linear (reg-prefetch pipeline); WT writes fp16 + transposed fp16 copy ----------------
template<bool WT>
__global__ __launch_bounds__(256)
void k_linear(const float* __restrict__ X, const short* __restrict__ WTh,
              const short* __restrict__ WTl, const float* __restrict__ bias,
              float* __restrict__ Y, short* __restrict__ Yf,
              short* __restrict__ YT)
{
    __shared__ __align__(16) short SMEM[4 * 128 * LDT];
    short* Ah = SMEM;
    short* Al = SMEM + 128 * LDT;
    short* Bh = SMEM + 2 * 128 * LDT;
    short* Bl = SMEM + 3 * 128 * LDT;
    const int t = threadIdx.x;
    const int m0 = (int)(blockIdx.x >> 2) * 128;
    const int n0 = (int)(blockIdx.x & 3) * 128;
    const int lane = t & 63;
    const int wr = (t >> 7) & 1, wc = (t >> 6) & 1;
    const int fr = lane & 15, fg = lane >> 4;
    const int srow = t >> 1, sk = (t & 1) * 16;

    f32x4 acc[4][4] = {};

    float4 fX[4];
    bf16x8 fWh[2], fWl[2];
    bf16x8 hiR[2], loR[2];
    auto load_raw = [&](int k0) {
        const float* src = X + (size_t)(m0 + srow) * 512 + k0 + sk;
        #pragma unroll
        for (int i = 0; i < 4; i++) fX[i] = ((const float4*)src)[i];
        const short* sh = WTh + (size_t)(n0 + srow) * 512 + k0 + sk;
        const short* sl = WTl + (size_t)(n0 + srow) * 512 + k0 + sk;
        fWh[0] = ((const bf16x8*)sh)[0]; fWh[1] = ((const bf16x8*)sh)[1];
        fWl[0] = ((const bf16x8*)sl)[0]; fWl[1] = ((const bf16x8*)sl)[1];
    };
    auto split_cvt = [&]() {
        const float* fv = (const float*)fX;
        short hi[16], lo[16];
        #pragma unroll
        for (int j = 0; j < 16; j++) {
            float x = fv[j];
            short h = f2bf(x);
            hi[j] = h; lo[j] = f2bf(x - bf2f(h));
        }
        hiR[0] = *(bf16x8*)&hi[0]; hiR[1] = *(bf16x8*)&hi[8];
        loR[0] = *(bf16x8*)&lo[0]; loR[1] = *(bf16x8*)&lo[8];
    };

    load_raw(0);
    split_cvt();

    for (int k0 = 0; k0 < 512; k0 += 32) {
        __syncthreads();
        *(bf16x8*)&Ah[srow * LDT + sk]     = hiR[0];
        *(bf16x8*)&Ah[srow * LDT + sk + 8] = hiR[1];
        *(bf16x8*)&Al[srow * LDT + sk]     = loR[0];
        *(bf16x8*)&Al[srow * LDT + sk + 8] = loR[1];
        *(bf16x8*)&Bh[srow * LDT + sk]     = fWh[0];
        *(bf16x8*)&Bh[srow * LDT + sk + 8] = fWh[1];
        *(bf16x8*)&Bl[srow * LDT + sk]     = fWl[0];
        *(bf16x8*)&Bl[srow * LDT + sk + 8] = fWl[1];
        __syncthreads();
        const bool more = (k0 + 32) < 512;
        if (more) load_raw(k0 + 32);       // loads retire under the MFMA below
        bf16x8 a_h[4], a_l[4], b_h[4], b_l[4];
        #pragma unroll
        for (int i = 0; i < 4; i++) {
            int ar = (wr * 64 + i * 16 + fr) * LDT + fg * 8;
            int br = (wc * 64 + i * 16 + fr) * LDT + fg * 8;
            a_h[i] = *(const bf16x8*)&Ah[ar];
            a_l[i] = *(const bf16x8*)&Al[ar];
            b_h[i] = *(const bf16x8*)&Bh[br];
            b_l[i] = *(const bf16x8*)&Bl[br];
        }
        #pragma unroll
        for (int mi = 0; mi < 4; mi++)
        #pragma unroll
        for (int ni = 0; ni < 4; ni++) {
            acc[mi][ni] = __builtin_amdgcn_mfma_f32_16x16x32_bf16(a_h[mi], b_h[ni], acc[mi][ni], 0, 0, 0);
            acc[mi][ni] = __builtin_amdgcn_mfma_f32_16x16x32_bf16(a_h[mi], b_l[ni], acc[mi][ni], 0, 0, 0);
            acc[mi][ni] = __builtin_amdgcn_mfma_f32_16x16x32_bf16(a_l[mi], b_h[ni], acc[mi][ni], 0, 0, 0);
        }
        if (more) split_cvt();             // conversion VALU also overlapped
    }
    float bv[4];
    #pragma unroll
    for (int ni = 0; ni < 4; ni++) bv[ni] = bias[n0 + wc * 64 + ni * 16 + fr];

    if (!WT) {
        #pragma unroll
        for (int mi = 0; mi < 4; mi++)
        #pragma unroll
        for (int r = 0; r < 4; r++) {
            int row = m0 + wr * 64 + mi * 16 + fg * 4 + r;
            #pragma unroll
            for (int ni = 0; ni < 4; ni++)
                Y[(size_t)row * 512 + n0 + wc * 64 + ni * 16 + fr] =
                    fmaxf(acc[mi][ni][r] + bv[ni], 0.f);
        }
    } else {
        #pragma unroll
        for (int mi = 0; mi < 4; mi++)
        #pragma unroll
        for (int r = 0; r < 4; r++) {
            int row = m0 + wr * 64 + mi * 16 + fg * 4 + r;
            #pragma unroll
            for (int ni = 0; ni < 4; ni++) {
                float v = fmaxf(acc[mi][ni][r] + bv[ni], 0.f);
                size_t o = (size_t)row * 512 + n0 + wc * 64 + ni * 16 + fr;
                Yf[o] = f2h(v);     // fp16 copy for the scoat logits GEMM
            }
        }
        __syncthreads();
        short* TT = SMEM;
        #pragma unroll
        for (int mi = 0; mi < 4; mi++)
        #pragma unroll
        for (int r = 0; r < 4; r++) {
            int ml = wr * 64 + mi * 16 + fg * 4 + r;
            #pragma unroll
            for (int ni = 0; ni < 4; ni++)
                TT[(wc * 64 + ni * 16 + fr) * 136 + ml] =
                    f2h(fmaxf(acc[mi][ni][r] + bv[ni], 0.f));
        }
        __syncthreads();
        const int n = t >> 1, half = t & 1;
        const int nm = (n & 64) + p64(n & 63);   // permuted destination row
        short* dst = YT + ((size_t)(m0 >> 7) * 512 + n0 + nm) * 128 + half * 64;
        #pragma unroll
        for (int j = 0; j < 8; j++)
            *(bf16x8*)(dst + j * 8) = *(const bf16x8*)&TT[n * 136 + half * 64 + j * 8];
    }
}

// ---------------- DUAL logits GEMM (reg-prefetch pipeline): one c read -> both pipelines ----------------
__global__ __launch_bounds__(256, 2)
void k_att_dual(const float* __restrict__ Cc, const short* __restrict__ B1g,
                const short* __restrict__ B2g, const float* __restrict__ cwv,
                const float* __restrict__ s1pg, const float* __restrict__ biasp,
                const int* __restrict__ qmask, const int* __restrict__ cmask,
                short* __restrict__ c16,
                short* __restrict__ Pr1, short* __restrict__ Pe1, float2* __restrict__ cp1,
                short* __restrict__ Pr2, short* __restrict__ Pe2, float2* __restrict__ cp2)
{
    __shared__ __align__(16) short SM[128 * 136];   // staging 3*128*LDT=30720B | bounce 34816B
    short* Ah  = SM;
    short* B1h = SM + 128 * LDT;
    short* B2h = SM + 2 * 128 * LDT;
    short* TT  = SM;
    __shared__ float red[2][128];
    __shared__ float mrowL[128], rinvL[128], cmaxL[128];
    __shared__ float cws[512];
    __shared__ float s0red[128][2];
    __shared__ float s0L[128], s1L[128];
    __shared__ int qmsL[128], cmsL[128];

    const int t = threadIdx.x;
    const int b  = (int)(blockIdx.x & 63);      // 8 chunks of b land on one XCD
    const int ch = (int)(blockIdx.x >> 6);
    const int m0 = ch * 128;
    const int lane = t & 63;
    const int wr = (t >> 7) & 1, wc = (t >> 6) & 1;
    const int fr = lane & 15, fg = lane >> 4;
    const int srow = t >> 1, sk = (t & 1) * 16;

    cws[t] = cwv[t]; cws[t + 256] = cwv[t + 256];
    if (t < 128) {
        qmsL[t] = qmask[b * 128 + t];
        cmsL[t] = cmask[b * 1024 + m0 + t];
        s1L[t] = s1pg[((size_t)b * 4 + 0) * 128 + t] + s1pg[((size_t)b * 4 + 1) * 128 + t]
               + s1pg[((size_t)b * 4 + 2) * 128 + t] + s1pg[((size_t)b * 4 + 3) * 128 + t];
    }

    const size_t aoff = ((size_t)b * 1024 + m0 + srow) * 512;
    const size_t boff = ((size_t)b * 128 + srow) * 512;
    float s0part = 0.f;
    f32x4 acc1[4][4] = {}, acc2[4][4] = {};

    float4 fA[4];
    uint4 fB1[2], fB2[2];
    bf16x8 hvR[2];
    auto load_raw = [&](int k0) {
        const float* src = Cc + aoff + k0 + sk;
        #pragma unroll
        for (int i = 0; i < 4; i++) fA[i] = ((const float4*)src)[i];
        fB1[0] = *(const uint4*)(B1g + boff + k0 + sk);
        fB1[1] = *(const uint4*)(B1g + boff + k0 + sk + 8);
        fB2[0] = *(const uint4*)(B2g + boff + k0 + sk);
        fB2[1] = *(const uint4*)(B2g + boff + k0 + sk + 8);
    };
    auto cvt_exp = [&](int k0) {
        const float* fv = (const float*)fA;
        short hv[16];
        #pragma unroll
        for (int j = 0; j < 16; j++) {
            float x = fv[j];
            s0part += x * cws[k0 + sk + j];
            hv[j] = f2h(x);
        }
        hvR[0] = *(bf16x8*)&hv[0]; hvR[1] = *(bf16x8*)&hv[8];
        *(bf16x8*)(c16 + aoff + k0 + sk)     = hvR[0];
        *(bf16x8*)(c16 + aoff + k0 + sk + 8) = hvR[1];
    };

    load_raw(0);
    cvt_exp(0);

    for (int k0 = 0; k0 < 512; k0 += 32) {
        __syncthreads();
        *(bf16x8*)&Ah[srow * LDT + sk]      = hvR[0];
        *(bf16x8*)&Ah[srow * LDT + sk + 8]  = hvR[1];
        *(uint4*)&B1h[srow * LDT + sk]      = fB1[0];
        *(uint4*)&B1h[srow * LDT + sk + 8]  = fB1[1];
        *(uint4*)&B2h[srow * LDT + sk]      = fB2[0];
        *(uint4*)&B2h[srow * LDT + sk + 8]  = fB2[1];
        __syncthreads();
        const bool more = (k0 + 32) < 512;
        if (more) load_raw(k0 + 32);       // loads retire under the MFMA below
        #pragma unroll
        for (int i = 0; i < 4; i++) {
            f16x8 a_ = *(const f16x8*)&Ah[(wr * 64 + i * 16 + fr) * LDT + fg * 8];
            #pragma unroll
            for (int ni = 0; ni < 4; ni++) {
                int br = (wc * 64 + ni * 16 + fr) * LDT + fg * 8;
                f16x8 b1_ = *(const f16x8*)&B1h[br];
                acc1[i][ni] = __builtin_amdgcn_mfma_f32_16x16x32_f16(a_, b1_, acc1[i][ni], 0, 0, 0);
                f16x8 b2_ = *(const f16x8*)&B2h[br];
                acc2[i][ni] = __builtin_amdgcn_mfma_f32_16x16x32_f16(a_, b2_, acc2[i][ni], 0, 0, 0);
            }
        }
        if (more) cvt_exp(k0 + 32);        // cvt + s0 + c16 store also overlapped
    }

    // ---- s0/s1/bias additive terms (sim pipeline only) ----
    s0red[srow][t & 1] = s0part;
    __syncthreads();
    if (t < 128) s0L[t] = s0red[t][0] + s0red[t][1];
    __syncthreads();
    {
        float b0 = biasp[0];
        #pragma unroll
        for (int mi = 0; mi < 4; mi++)
        #pragma unroll
        for (int r = 0; r < 4; r++) {
            float s0r = s0L[wr * 64 + mi * 16 + fg * 4 + r] + b0;
            #pragma unroll
            for (int ni = 0; ni < 4; ni++)
                acc1[mi][ni][r] += s0r + s1L[wc * 64 + ni * 16 + fr];
        }
    }

    bool qmv[4];
    #pragma unroll
    for (int ni = 0; ni < 4; ni++) qmv[ni] = qmsL[wc * 64 + ni * 16 + fr] != 0;
    bool cmb[4][4];
    #pragma unroll
    for (int mi = 0; mi < 4; mi++)
    #pragma unroll
    for (int r = 0; r < 4; r++) cmb[mi][r] = cmsL[wr * 64 + mi * 16 + fg * 4 + r] != 0;

    auto emit = [&](f32x4 (&acc)[4][4], short* __restrict__ Pr,
                    short* __restrict__ Pe, float2* __restrict__ cpart_g) {
        __syncthreads();    // protect red/TT from previous pipeline's readers
        // ---- row softmax ----
        #pragma unroll
        for (int mi = 0; mi < 4; mi++)
        #pragma unroll
        for (int r = 0; r < 4; r++) {
            float m = NEGV;
            #pragma unroll
            for (int ni = 0; ni < 4; ni++) if (qmv[ni]) m = fmaxf(m, acc[mi][ni][r]);
            #pragma unroll
            for (int off = 1; off < 16; off <<= 1) m = fmaxf(m, __shfl_xor(m, off));
            if (fr == 0) red[wc][wr * 64 + mi * 16 + fg * 4 + r] = m;
        }
        __syncthreads();
        if (t < 128) mrowL[t] = fmaxf(red[0][t], red[1][t]);
        __syncthreads();
        #pragma unroll
        for (int mi = 0; mi < 4; mi++)
        #pragma unroll
        for (int r = 0; r < 4; r++) {
            float mr = mrowL[wr * 64 + mi * 16 + fg * 4 + r];
            float s = 0.f;
            #pragma unroll
            for (int ni = 0; ni < 4; ni++) if (qmv[ni]) s += __expf(acc[mi][ni][r] - mr);
            #pragma unroll
            for (int off = 1; off < 16; off <<= 1) s += __shfl_xor(s, off);
            if (fr == 0) red[wc][wr * 64 + mi * 16 + fg * 4 + r] = s;
        }
        __syncthreads();
        if (t < 128) rinvL[t] = 1.f / (red[0][t] + red[1][t]);
        __syncthreads();
        #pragma unroll
        for (int mi = 0; mi < 4; mi++)
        #pragma unroll
        for (int r = 0; r < 4; r++) {
            int rowl = wr * 64 + mi * 16 + fg * 4 + r;
            float mr = mrowL[rowl], iv = rinvL[rowl];
            size_t obase = ((size_t)b * 1024 + m0 + rowl) * 128;
            #pragma unroll
            for (int ni = 0; ni < 4; ni++) {
                float o = qmv[ni] ? __expf(acc[mi][ni][r] - mr) * iv : 0.f;
                Pr[obase + wc * 64 + ni * 16 + fr] = f2h(o);
            }
        }
        // ---- column pass: chunk max, raw exp(v - M_ch) transposed out ----
        float cpart[4];
        #pragma unroll
        for (int ni = 0; ni < 4; ni++) {
            float m = NEGV;
            #pragma unroll
            for (int mi = 0; mi < 4; mi++)
            #pragma unroll
            for (int r = 0; r < 4; r++) if (cmb[mi][r]) m = fmaxf(m, acc[mi][ni][r]);
            m = fmaxf(m, __shfl_xor(m, 16));
            m = fmaxf(m, __shfl_xor(m, 32));
            cpart[ni] = m;
        }
        if (fg == 0) {
            #pragma unroll
            for (int ni = 0; ni < 4; ni++) red[wr][wc * 64 + ni * 16 + fr] = cpart[ni];
        }
        __syncthreads();
        if (t < 128) cmaxL[t] = fmaxf(red[0][t], red[1][t]);
        __syncthreads();
        #pragma unroll
        for (int ni = 0; ni < 4; ni++) {
            const int q = wc * 64 + ni * 16 + fr;
            float cm = cmaxL[q];
            float s = 0.f;
            #pragma unroll
            for (int mi = 0; mi < 4; mi++)
            #pragma unroll
            for (int r = 0; r < 4; r++) {
                int rloc = wr * 64 + mi * 16 + fg * 4 + r;
                float e = cmb[mi][r] ? __expf(acc[mi][ni][r] - cm) : 0.f;
                s += e;
                TT[q * 136 + rloc] = f2h(e);
            }
            s += __shfl_xor(s, 16);
            s += __shfl_xor(s, 32);
            cpart[ni] = s;
        }
        __syncthreads();
        if (fg == 0) {
            #pragma unroll
            for (int ni = 0; ni < 4; ni++) red[wr][wc * 64 + ni * 16 + fr] = cpart[ni];
        }
        __syncthreads();
        {   // coalesced transposed write of the exp-shifted chunk
            const int q2 = t >> 1, half = t & 1;
            short* dst = Pe + ((size_t)b * 128 + q2) * 1024 + m0 + half * 64;
            #pragma unroll
            for (int j = 0; j < 8; j++)
                *(bf16x8*)(dst + j * 8) = *(const bf16x8*)&TT[q2 * 136 + half * 64 + j * 8];
        }
        if (t < 128) cpart_g[((size_t)b * 8 + ch) * 128 + t] = make_float2(cmaxL[t], red[0][t] + red[1][t]);
    };

    emit(acc1, Pr1, Pe1, cp1);
    emit(acc2, Pr2, Pe2, cp2);
}

// ---------------- fused dual K=1024 GEMM (c16 input) with inline column-softmax normalization ----------------
__global__ __launch_bounds__(256)
void k_kgemm2(const short* __restrict__ A1, const short* __restrict__ A2,
              const short* __restrict__ C16, const float2* __restrict__ cpS,
              const float2* __restrict__ cpC, short* __restrict__ Y1T,
              short* __restrict__ Y2T)
{
    __shared__ __align__(16) short Bs[2][64 * LDT];
    __shared__ __align__(16) short TT[64 * 136];
    __shared__ float wtr[2][8][128];
    __shared__ float fin[2][128];
    const int t = threadIdx.x;
    const int b  = (int)(blockIdx.x & 63);
    const int n0 = (int)(blockIdx.x >> 6) * 64;
    const int lane = t & 63;
    const int w  = t >> 6;
    const int wr = w >> 1, wc = w & 1;
    const int fr = lane & 15, fg = lane >> 4;
    const int n4 = (t & 15) * 4, kk2 = (t >> 4) * 2;

    {   // normalization tables
        const int tb = t >> 7, qq = t & 127;
        const float2* cp = tb ? cpC : cpS;
        float2 pc[8];
        #pragma unroll
        for (int c2 = 0; c2 < 8; c2++) pc[c2] = cp[((size_t)b * 8 + c2) * 128 + qq];
        float Mg = NEGV;
        #pragma unroll
        for (int c2 = 0; c2 < 8; c2++) Mg = fmaxf(Mg, pc[c2].x);
        float Sg = 0.f;
        #pragma unroll
        for (int c2 = 0; c2 < 8; c2++) Sg += pc[c2].y * __expf(pc[c2].x - Mg);
        const float clampv = Mg - 60.f;
        float mh[8];
        #pragma unroll
        for (int c2 = 0; c2 < 8; c2++) mh[c2] = fmaxf(pc[c2].x, clampv);
        wtr[tb][0][qq] = 1.f;
        #pragma unroll
        for (int c2 = 1; c2 < 8; c2++) wtr[tb][c2][qq] = __expf(mh[c2 - 1] - mh[c2]);
        fin[tb][qq] = (Sg > 0.f) ? __expf(mh[7] - Mg) / Sg : 0.f;
    }

    f32x4 acc1[4][2] = {}, acc2[4][2] = {};

    auto load_e = [&](int k0, uint2* e) {
        const short* p = C16 + ((size_t)b * 1024 + k0 + kk2) * 512 + n0 + n4;
        e[0] = *(const uint2*)(p);
        e[1] = *(const uint2*)(p + 512);
    };
    auto store_b = [&](const uint2* e, int buf) {
        const unsigned short* r0 = (const unsigned short*)&e[0];
        const unsigned short* r1 = (const unsigned short*)&e[1];
        #pragma unroll
        for (int l = 0; l < 4; l++)
            *(unsigned*)&Bs[buf][(n4 + l) * LDT + kk2] = (unsigned)r0[l] | ((unsigned)r1[l] << 16);
    };

    {
        uint2 e[2];
        load_e(0, e);
        store_b(e, 0);
    }
    __syncthreads();

    for (int k0 = 0; k0 < 1024; k0 += 32) {
        const int cur = (k0 >> 5) & 1;
        const bool more = (k0 + 32) < 1024;
        uint2 e[2];
        if (more) load_e(k0 + 32, e);
        if (k0 && (k0 & 127) == 0) {     // chunk boundary: rescale accumulators
            const int c2 = k0 >> 7;
            #pragma unroll
            for (int mi = 0; mi < 4; mi++)
            #pragma unroll
            for (int r = 0; r < 4; r++) {
                int qq = wr * 64 + mi * 16 + fg * 4 + r;
                float f1 = wtr[0][c2][qq], f2 = wtr[1][c2][qq];
                #pragma unroll
                for (int ni = 0; ni < 2; ni++) {
                    acc1[mi][ni][r] *= f1;
                    acc2[mi][ni][r] *= f2;
                }
            }
        }
        f16x8 a1[4], a2[4], bg[2];
        #pragma unroll
        for (int i = 0; i < 4; i++) {
            size_t arow = (size_t)(b * 128 + wr * 64 + i * 16 + fr) * 1024 + k0 + fg * 8;
            a1[i] = *(const f16x8*)(A1 + arow);
            a2[i] = *(const f16x8*)(A2 + arow);
        }
        #pragma unroll
        for (int i = 0; i < 2; i++)
            bg[i] = *(const f16x8*)&Bs[cur][(wc * 32 + i * 16 + fr) * LDT + fg * 8];
        #pragma unroll
        for (int mi = 0; mi < 4; mi++)
        #pragma unroll
        for (int ni = 0; ni < 2; ni++) {
            acc1[mi][ni] = __builtin_amdgcn_mfma_f32_16x16x32_f16(a1[mi], bg[ni], acc1[mi][ni], 0, 0, 0);
            acc2[mi][ni] = __builtin_amdgcn_mfma_f32_16x16x32_f16(a2[mi], bg[ni], acc2[mi][ni], 0, 0, 0);
        }
        if (more) store_b(e, cur ^ 1);
        __syncthreads();
    }

    // transpose-bounce both outputs -> coalesced [B,512,128] fp16 (h-permuted rows), final scale
    const int n_l = t >> 2, qu = t & 3;
    const int nm = p64(n_l);
    #pragma unroll
    for (int mi = 0; mi < 4; mi++)
    #pragma unroll
    for (int r = 0; r < 4; r++) {
        int ml = wr * 64 + mi * 16 + fg * 4 + r;
        float fs = fin[0][ml];
        #pragma unroll
        for (int ni = 0; ni < 2; ni++)
            TT[(wc * 32 + ni * 16 + fr) * 136 + ml] = f2h(acc1[mi][ni][r] * fs);
    }
    __syncthreads();
    {
        short* dst = Y1T + ((size_t)b * 512 + n0 + nm) * 128 + qu * 32;
        #pragma unroll
        for (int j = 0; j < 4; j++)
            *(bf16x8*)(dst + j * 8) = *(const bf16x8*)&TT[n_l * 136 + qu * 32 + j * 8];
    }
    __syncthreads();
    #pragma unroll
    for (int mi = 0; mi < 4; mi++)
    #pragma unroll
    for (int r = 0; r < 4; r++) {
        int ml = wr * 64 + mi * 16 + fg * 4 + r;
        float fs = fin[1][ml];
        #pragma unroll
        for (int ni = 0; ni < 2; ni++)
            TT[(wc * 32 + ni * 16 + fr) * 136 + ml] = f2h(acc2[mi][ni][r] * fs);
    }
    __syncthreads();
    {
        short* dst = Y2T + ((size_t)b * 512 + n0 + nm) * 128 + qu * 32;
        #pragma unroll
        for (int j = 0; j < 4; j++)
            *(bf16x8*)(dst + j * 8) = *(const bf16x8*)&TT[n_l * 136 + qu * 32 + j * 8];
    }
}

// ---------------- merged epilogue GEMMs (K=128, fp16), 64-row tiles, two K-passes (low VGPR) ----------------
// part 0: writes [c, a, c*a, c*b] (channels 0,512,1024,1536); part 1: writes [scoat3, acoat] (2048, 2560).
__global__ __launch_bounds__(256)
void k_epi2(const short* __restrict__ s1s, const short* __restrict__ qT,
            const short* __restrict__ binT, const short* __restrict__ c16,
            const short* __restrict__ sc1, const short* __restrict__ qpT,
            const short* __restrict__ bcoT, float* __restrict__ out)
{
    const int bid = (int)blockIdx.x;
    const int part = bid & 1;
    const int lb = bid >> 1;
    const int hb = lb & 3, mb = (lb >> 2) & 15, b = lb >> 6;
    const int m0 = mb * 64, h0 = hb * 128;
    const int t = threadIdx.x;
    const int lane = t & 63;
    const int wr = (t >> 7) & 1, wc = (t >> 6) & 1;
    const int fr = lane & 15, fg = lane >> 4;

    const short* Abase  = (part ? sc1  : s1s) + ((size_t)b * 1024 + m0) * 128;
    const short* B1base = (part ? bcoT : qT)   + ((size_t)b * 512 + h0) * 128;
    const short* B2base = (part ? qpT  : binT) + ((size_t)b * 512 + h0) * 128;

    auto gemm = [&](const short* Bb, f32x4 (&acc)[2][4]) {
        #pragma unroll
        for (int kk = 0; kk < 4; kk++) {
            const int k0 = kk * 32;
            f16x8 af[2], bf[4];
            #pragma unroll
            for (int mi = 0; mi < 2; mi++)
                af[mi] = *(const f16x8*)(Abase + (size_t)(wr * 32 + mi * 16 + fr) * 128 + k0 + fg * 8);
            #pragma unroll
            for (int ni = 0; ni < 4; ni++)
                bf[ni] = *(const f16x8*)(Bb + (size_t)(wc * 64 + ni * 16 + fr) * 128 + k0 + fg * 8);
            #pragma unroll
            for (int mi = 0; mi < 2; mi++)
            #pragma unroll
            for (int ni = 0; ni < 4; ni++)
                acc[mi][ni] = __builtin_amdgcn_mfma_f32_16x16x32_f16(af[mi], bf[ni], acc[mi][ni], 0, 0, 0);
        }
    };

    const size_t crow_base = (size_t)b * 1024 + m0;
    const int colb = wc * 64 + fr * 4;       // logical column base (4 consecutive, via h-permutation)

    if (part == 0) {
        {   // pass 1: a = P @ qT  -> write c, a, c*a
            f32x4 acc[2][4] = {};
            gemm(B1base, acc);
            #pragma unroll
            for (int mi = 0; mi < 2; mi++)
            #pragma unroll
            for (int r = 0; r < 4; r++) {
                int rowl = wr * 32 + mi * 16 + fg * 4 + r;
                size_t obase = (crow_base + rowl) * 3072 + h0 + colb;
                f16x4 cv4 = *(const f16x4*)(c16 + (crow_base + rowl) * 512 + h0 + colb);
                float4 cv; cv.x = (float)cv4[0]; cv.y = (float)cv4[1]; cv.z = (float)cv4[2]; cv.w = (float)cv4[3];
                float4 av; av.x = acc[mi][0][r]; av.y = acc[mi][1][r]; av.z = acc[mi][2][r]; av.w = acc[mi][3][r];
                *(float4*)(out + obase) = cv;
                *(float4*)(out + obase + 512) = av;
                float4 ca; ca.x = cv.x * av.x; ca.y = cv.y * av.y; ca.z = cv.z * av.z; ca.w = cv.w * av.w;
                *(float4*)(out + obase + 1024) = ca;
            }
        }
        {   // pass 2: bterm = P @ binT -> write c*b
            f32x4 acc[2][4] = {};
            gemm(B2base, acc);
            #pragma unroll
            for (int mi = 0; mi < 2; mi++)
            #pragma unroll
            for (int r = 0; r < 4; r++) {
                int rowl = wr * 32 + mi * 16 + fg * 4 + r;
                size_t obase = (crow_base + rowl) * 3072 + h0 + colb;
                f16x4 cv4 = *(const f16x4*)(c16 + (crow_base + rowl) * 512 + h0 + colb);
                float4 cv; cv.x = (float)cv4[0]; cv.y = (float)cv4[1]; cv.z = (float)cv4[2]; cv.w = (float)cv4[3];
                float4 bv; bv.x = acc[mi][0][r]; bv.y = acc[mi][1][r]; bv.z = acc[mi][2][r]; bv.w = acc[mi][3][r];
                float4 cb; cb.x = cv.x * bv.x; cb.y = cv.y * bv.y; cb.z = cv.z * bv.z; cb.w = cv.w * bv.w;
                *(float4*)(out + obase + 1536) = cb;
            }
        }
    } else {
        {   // pass 1: scoat3 = sc1 @ bcoT -> channel 2048
            f32x4 acc[2][4] = {};
            gemm(B1base, acc);
            #pragma unroll
            for (int mi = 0; mi < 2; mi++)
            #pragma unroll
            for (int r = 0; r < 4; r++) {
                int rowl = wr * 32 + mi * 16 + fg * 4 + r;
                size_t obase = (crow_base + rowl) * 3072 + h0 + colb;
                float4 v; v.x = acc[mi][0][r]; v.y = acc[mi][1][r]; v.z = acc[mi][2][r]; v.w = acc[mi][3][r];
                *(float4*)(out + obase + 2048) = v;
            }
        }
        {   // pass 2: acoat = sc1 @ qpT -> channel 2560
            f32x4 acc[2][4] = {};
            gemm(B2base, acc);
            #pragma unroll
            for (int mi = 0; mi < 2; mi++)
            #pragma unroll
            for (int r = 0; r < 4; r++) {
                int rowl = wr * 32 + mi * 16 + fg * 4 + r;
                size_t obase = (crow_base + rowl) * 3072 + h0 + colb;
                float4 v; v.x = acc[mi][0][r]; v.y = acc[mi][1][r]; v.z = acc[mi][2][r]; v.w = acc[mi][3][r];
                *(float4*)(out + obase + 2560) = v;
            }
        }
    }
}

// ---------------- host launcher ----------------
extern "C" void kernel_launch(void* const* d_in, const int* in_sizes, int n_in,
                              void* d_out, int out_size, void* d_ws, size_t ws_size,
                              hipStream_t stream)
{
    const float* c     = (const float*)d_in[0];
    const float* q     = (const float*)d_in[1];
    const int*   cmask = (const int*)d_in[2];
    const int*   qmask = (const int*)d_in[3];
    const float* cwv   = (const float*)d_in[4];
    const float* qwv   = (const float*)d_in[5];
    const float* cqw   = (const float*)d_in[6];
    const float* bias  = (const float*)d_in[7];
    const float* W1    = (const float*)d_in[8];
    const float* b1    = (const float*)d_in[9];
    const float* W2    = (const float*)d_in[10];
    const float* b2    = (const float*)d_in[11];
    float* out = (float*)d_out;

    char* ws = (char*)d_ws;
    size_t off = 0;
    auto alloc = [&](size_t bytes) -> char* {
        char* p = ws + off;
        off = (off + bytes + 255) & ~(size_t)255;
        return p;
    };
    short* w1th = (short*)alloc(512 * 512 * 2);
    short* w1tl = (short*)alloc(512 * 512 * 2);
    short* w2th = (short*)alloc(512 * 512 * 2);
    short* w2tl = (short*)alloc(512 * 512 * 2);
    float* s1p  = (float*)alloc(64 * 4 * 128 * 4);
    short* q_cq = (short*)alloc((size_t)64 * 128 * 512 * 2);
    short* qT   = (short*)alloc((size_t)64 * 512 * 128 * 2);
    float* z1   = (float*)alloc((size_t)8192 * 512 * 4);     // layer-1 act; reused for binT/bcoT
    short* qp_f = (short*)alloc((size_t)8192 * 512 * 2);     // fp16 qp
    short* qpT  = (short*)alloc((size_t)64 * 512 * 128 * 2);
    short* c16  = (short*)alloc((size_t)64 * 1024 * 512 * 2);  // fp16 c (exported by k_att_dual)
    float2* colpartS = (float2*)alloc((size_t)64 * 8 * 128 * 8);
    float2* colpartC = (float2*)alloc((size_t)64 * 8 * 128 * 8);
    short* s1s  = (short*)alloc((size_t)64 * 1024 * 128 * 2);
    short* s2sT = (short*)alloc((size_t)64 * 128 * 1024 * 2);  // raw per-chunk exp (fp16)
    short* sc1  = (short*)alloc((size_t)64 * 1024 * 128 * 2);
    short* sc2T = (short*)alloc((size_t)64 * 128 * 1024 * 2);  // raw per-chunk exp (fp16)
    short* binT = (short*)z1;
    short* bcoT = ((short*)z1) + (size_t)64 * 512 * 128;

    k_prep_w<<<2048, 256, 0, stream>>>(W1, W2, w1th, w1tl, w2th, w2tl);
    k_prep_q<<<256, 256, 0, stream>>>(q, qwv, cqw, q_cq, qT, s1p);
    k_linear<false><<<256, 256, 0, stream>>>(q, w1th, w1tl, b1, z1, nullptr, nullptr);
    k_linear<true><<<256, 256, 0, stream>>>(z1, w2th, w2tl, b2, nullptr, qp_f, qpT);

    // merged logits pipelines: one c read, both GEMMs, c16 export (reg-prefetch K-loop)
    k_att_dual<<<512, 256, 0, stream>>>(
        c, q_cq, qp_f, cwv, s1p, bias, qmask, cmask, c16,
        s1s, s2sT, colpartS, sc1, sc2T, colpartC);

    // fused dual K=1024 GEMM (fp16 c16 input) with inline column-softmax normalization
    k_kgemm2<<<512, 256, 0, stream>>>(s2sT, sc2T, c16, colpartS, colpartC, binT, bcoT);

    // merged output epilogues: 64-row tiles, 2 K-passes, low VGPR -> 2x occupancy
    k_epi2<<<8192, 256, 0, stream>>>(s1s, qT, binT, c16, sc1, qpT, bcoT, out);
}

// Round 11
// 625.617 us; speedup vs baseline: 1.0046x; 1.0046x over previous
//
#include <hip/hip_runtime.h>
#include <cstdint>
#include <cstddef>

typedef short    bf16x8 __attribute__((ext_vector_type(8)));
typedef _Float16 f16x8  __attribute__((ext_vector_type(8)));
typedef _Float16 f16x4  __attribute__((ext_vector_type(4)));
typedef float    f32x4  __attribute__((ext_vector_type(4)));

#define NEGV (-1e30f)
#define LDT 40   // padded LDS row pitch (shorts) = 80B: 16B-aligned, 2-way-conflict max (free)

__device__ __forceinline__ short f2bf(float x){
    union { float f; unsigned u; } v; v.f = x;
    return (short)((v.u + 0x7fffu + ((v.u >> 16) & 1u)) >> 16);
}
__device__ __forceinline__ float bf2f(short h){
    union { float f; unsigned u; } v; v.u = ((unsigned)(unsigned short)h) << 16; return v.f;
}
__device__ __forceinline__ short f2h(float x){
    _Float16 h = (_Float16)x;
    union { _Float16 h; unsigned short u; } v; v.h = h;
    return (short)v.u;
}
__device__ __forceinline__ unsigned packh(float a, float b){
    return (unsigned)(unsigned short)f2h(a) | ((unsigned)(unsigned short)f2h(b) << 16);
}
// memory row (within a 64-row group) holding logical column h:
// epi's B-fragment load at row ni*16+fr then yields logical col fr*4+ni (consecutive per thread)
__device__ __forceinline__ int p64(int x){ return ((x & 3) << 4) | (x >> 2); }

// ---------------- prep: W1,W2 -> transposed bf16 hi/lo (MLP stays split-bf16) ----------------
__global__ __launch_bounds__(256)
void k_prep_w(const float* __restrict__ W1, const float* __restrict__ W2,
              short* __restrict__ W1Th, short* __restrict__ W1Tl,
              short* __restrict__ W2Th, short* __restrict__ W2Tl)
{
    int idx = blockIdx.x * 256 + threadIdx.x;
    int w = idx >> 18;
    int e = idx & ((1 << 18) - 1);
    int n = e & 511, k = e >> 9;
    const float* W = w ? W2 : W1;
    float x = W[k * 512 + n];
    short hi = f2bf(x);
    short lo = f2bf(x - bf2f(hi));
    size_t o = (size_t)n * 512 + k;
    if (w) { W2Th[o] = hi; W2Tl[o] = lo; } else { W1Th[o] = hi; W1Tl[o] = lo; }
}

// ---------------- prep q: qT (fp16, transposed, h-permuted), q_cq = f16(q*cqw), s1 partials ----------------
__global__ __launch_bounds__(256)
void k_prep_q(const float* __restrict__ q, const float* __restrict__ qwv,
              const float* __restrict__ cqw, short* __restrict__ q_cq,
              short* __restrict__ qT, float* __restrict__ s1p)
{
    __shared__ short TT[128 * 136];
    __shared__ float qws[128], cqs[128];
    const int t = threadIdx.x;
    const int b = (int)(blockIdx.x >> 2), hb = (int)(blockIdx.x & 3), h0 = hb * 128;
    if (t < 128) { qws[t] = qwv[h0 + t]; cqs[t] = cqw[h0 + t]; }
    __syncthreads();
    #pragma unroll
    for (int it = 0; it < 16; it++) {
        int idx = it * 256 + t;
        int m = idx >> 5, c4 = (idx & 31) * 4;
        float4 v = *(const float4*)(q + ((size_t)b * 128 + m) * 512 + h0 + c4);
        TT[(c4 + 0) * 136 + m] = f2h(v.x);
        TT[(c4 + 1) * 136 + m] = f2h(v.y);
        TT[(c4 + 2) * 136 + m] = f2h(v.z);
        TT[(c4 + 3) * 136 + m] = f2h(v.w);
        uint2 d;
        d.x = packh(v.x * cqs[c4],     v.y * cqs[c4 + 1]);
        d.y = packh(v.z * cqs[c4 + 2], v.w * cqs[c4 + 3]);
        *(uint2*)(q_cq + ((size_t)b * 128 + m) * 512 + h0 + c4) = d;
        float dot = v.x * qws[c4] + v.y * qws[c4 + 1] + v.z * qws[c4 + 2] + v.w * qws[c4 + 3];
        #pragma unroll
        for (int off = 1; off < 32; off <<= 1) dot += __shfl_xor(dot, off);
        if ((t & 31) == 0) s1p[((size_t)b * 4 + hb) * 128 + m] = dot;
    }
    __syncthreads();
    const int h = t >> 1, half = t & 1;
    const int hm = (h & 64) + p64(h & 63);   // permuted destination row
    short* dst = qT + ((size_t)b * 512 + h0 + hm) * 128 + half * 64;
    #pragma unroll
    for (int j = 0; j < 8; j++)
        *(bf16x8*)(dst + j * 8) = *(const bf16x8*)&TT[h * 136 + half * 64 + j * 8];
}

// ---------------- split-bf16 linear (reg-prefetch pipeline); WT writes fp16 + transposed fp16 copy ----------------
template<bool WT>
__global__ __launch_bounds__(256)
void k_linear(const float* __restrict__ X, const short* __restrict__ WTh,
              const short* __restrict__ WTl, const float* __restrict__ bias,
              float* __restrict__ Y, short* __restrict__ Yf,
              short* __restrict__ YT)
{
    __shared__ __align__(16) short SMEM[4 * 128 * LDT];
    short* Ah = SMEM;
    short* Al = SMEM + 128 * LDT;
    short* Bh = SMEM + 2 * 128 * LDT;
    short* Bl = SMEM + 3 * 128 * LDT;
    const int t = threadIdx.x;
    const int m0 = (int)(blockIdx.x >> 2) * 128;
    const int n0 = (int)(blockIdx.x & 3) * 128;
    const int lane = t & 63;
    const int wr = (t >> 7) & 1, wc = (t >> 6) & 1;
    const int fr = lane & 15, fg = lane >> 4;
    const int srow = t >> 1, sk = (t & 1) * 16;

    f32x4 acc[4][4] = {};

    float4 fX[4];
    bf16x8 fWh[2], fWl[2];
    bf16x8 hiR[2], loR[2];
    auto load_raw = [&](int k0) {
        const float* src = X + (size_t)(m0 + srow) * 512 + k0 + sk;
        #pragma unroll
        for (int i = 0; i < 4; i++) fX[i] = ((const float4*)src)[i];
        const short* sh = WTh + (size_t)(n0 + srow) * 512 + k0 + sk;
        const short* sl = WTl + (size_t)(n0 + srow) * 512 + k0 + sk;
        fWh[0] = ((const bf16x8*)sh)[0]; fWh[1] = ((const bf16x8*)sh)[1];
        fWl[0] = ((const bf16x8*)sl)[0]; fWl[1] = ((const bf16x8*)sl)[1];
    };
    auto split_cvt = [&]() {
        const float* fv = (const float*)fX;
        short hi[16], lo[16];
        #pragma unroll
        for (int j = 0; j < 16; j++) {
            float x = fv[j];
            short h = f2bf(x);
            hi[j] = h; lo[j] = f2bf(x - bf2f(h));
        }
        hiR[0] = *(bf16x8*)&hi[0]; hiR[1] = *(bf16x8*)&hi[8];
        loR[0] = *(bf16x8*)&lo[0]; loR[1] = *(bf16x8*)&lo[8];
    };

    load_raw(0);
    split_cvt();

    for (int k0 = 0; k0 < 512; k0 += 32) {
        __syncthreads();
        *(bf16x8*)&Ah[srow * LDT + sk]     = hiR[0];
        *(bf16x8*)&Ah[srow * LDT + sk + 8] = hiR[1];
        *(bf16x8*)&Al[srow * LDT + sk]     = loR[0];
        *(bf16x8*)&Al[srow * LDT + sk + 8] = loR[1];
        *(bf16x8*)&Bh[srow * LDT + sk]     = fWh[0];
        *(bf16x8*)&Bh[srow * LDT + sk + 8] = fWh[1];
        *(bf16x8*)&Bl[srow * LDT + sk]     = fWl[0];
        *(bf16x8*)&Bl[srow * LDT + sk + 8] = fWl[1];
        __syncthreads();
        const bool more = (k0 + 32) < 512;
        if (more) load_raw(k0 + 32);       // loads retire under the MFMA below
        bf16x8 a_h[4], a_l[4], b_h[4], b_l[4];
        #pragma unroll
        for (int i = 0; i < 4; i++) {
            int ar = (wr * 64 + i * 16 + fr) * LDT + fg * 8;
            int br = (wc * 64 + i * 16 + fr) * LDT + fg * 8;
            a_h[i] = *(const bf16x8*)&Ah[ar];
            a_l[i] = *(const bf16x8*)&Al[ar];
            b_h[i] = *(const bf16x8*)&Bh[br];
            b_l[i] = *(const bf16x8*)&Bl[br];
        }
        #pragma unroll
        for (int mi = 0; mi < 4; mi++)
        #pragma unroll
        for (int ni = 0; ni < 4; ni++) {
            acc[mi][ni] = __builtin_amdgcn_mfma_f32_16x16x32_bf16(a_h[mi], b_h[ni], acc[mi][ni], 0, 0, 0);
            acc[mi][ni] = __builtin_amdgcn_mfma_f32_16x16x32_bf16(a_h[mi], b_l[ni], acc[mi][ni], 0, 0, 0);
            acc[mi][ni] = __builtin_amdgcn_mfma_f32_16x16x32_bf16(a_l[mi], b_h[ni], acc[mi][ni], 0, 0, 0);
        }
        if (more) split_cvt();             // conversion VALU also overlapped
    }
    float bv[4];
    #pragma unroll
    for (int ni = 0; ni < 4; ni++) bv[ni] = bias[n0 + wc * 64 + ni * 16 + fr];

    if (!WT) {
        #pragma unroll
        for (int mi = 0; mi < 4; mi++)
        #pragma unroll
        for (int r = 0; r < 4; r++) {
            int row = m0 + wr * 64 + mi * 16 + fg * 4 + r;
            #pragma unroll
            for (int ni = 0; ni < 4; ni++)
                Y[(size_t)row * 512 + n0 + wc * 64 + ni * 16 + fr] =
                    fmaxf(acc[mi][ni][r] + bv[ni], 0.f);
        }
    } else {
        #pragma unroll
        for (int mi = 0; mi < 4; mi++)
        #pragma unroll
        for (int r = 0; r < 4; r++) {
            int row = m0 + wr * 64 + mi * 16 + fg * 4 + r;
            #pragma unroll
            for (int ni = 0; ni < 4; ni++) {
                float v = fmaxf(acc[mi][ni][r] + bv[ni], 0.f);
                size_t o = (size_t)row * 512 + n0 + wc * 64 + ni * 16 + fr;
                Yf[o] = f2h(v);     // fp16 copy for the scoat logits GEMM
            }
        }
        __syncthreads();
        short* TT = SMEM;
        #pragma unroll
        for (int mi = 0; mi < 4; mi++)
        #pragma unroll
        for (int r = 0; r < 4; r++) {
            int ml = wr * 64 + mi * 16 + fg * 4 + r;
            #pragma unroll
            for (int ni = 0; ni < 4; ni++)
                TT[(wc * 64 + ni * 16 + fr) * 136 + ml] =
                    f2h(fmaxf(acc[mi][ni][r] + bv[ni], 0.f));
        }
        __syncthreads();
        const int n = t >> 1, half = t & 1;
        const int nm = (n & 64) + p64(n & 63);   // permuted destination row
        short* dst = YT + ((size_t)(m0 >> 7) * 512 + n0 + nm) * 128 + half * 64;
        #pragma unroll
        for (int j = 0; j < 8; j++)
            *(bf16x8*)(dst + j * 8) = *(const bf16x8*)&TT[n * 136 + half * 64 + j * 8];
    }
}

// ---------------- DUAL logits GEMM (reg-prefetch pipeline): one c read -> both pipelines ----------------
__global__ __launch_bounds__(256, 2)
void k_att_dual(const float* __restrict__ Cc, const short* __restrict__ B1g,
                const short* __restrict__ B2g, const float* __restrict__ cwv,
                const float* __restrict__ s1pg, const float* __restrict__ biasp,
                const int* __restrict__ qmask, const int* __restrict__ cmask,
                short* __restrict__ c16,
                short* __restrict__ Pr1, short* __restrict__ Pe1, float2* __restrict__ cp1,
                short* __restrict__ Pr2, short* __restrict__ Pe2, float2* __restrict__ cp2)
{
    __shared__ __align__(16) short SM[128 * 136];   // staging 3*128*LDT=30720B | bounce 34816B
    short* Ah  = SM;
    short* B1h = SM + 128 * LDT;
    short* B2h = SM + 2 * 128 * LDT;
    short* TT  = SM;
    __shared__ float red[2][128];
    __shared__ float mrowL[128], rinvL[128], cmaxL[128];
    __shared__ float cws[512];
    __shared__ float s0red[128][2];
    __shared__ float s0L[128], s1L[128];
    __shared__ int qmsL[128], cmsL[128];

    const int t = threadIdx.x;
    const int b  = (int)(blockIdx.x & 63);      // 8 chunks of b land on one XCD
    const int ch = (int)(blockIdx.x >> 6);
    const int m0 = ch * 128;
    const int lane = t & 63;
    const int wr = (t >> 7) & 1, wc = (t >> 6) & 1;
    const int fr = lane & 15, fg = lane >> 4;
    const int srow = t >> 1, sk = (t & 1) * 16;

    cws[t] = cwv[t]; cws[t + 256] = cwv[t + 256];
    if (t < 128) {
        qmsL[t] = qmask[b * 128 + t];
        cmsL[t] = cmask[b * 1024 + m0 + t];
        s1L[t] = s1pg[((size_t)b * 4 + 0) * 128 + t] + s1pg[((size_t)b * 4 + 1) * 128 + t]
               + s1pg[((size_t)b * 4 + 2) * 128 + t] + s1pg[((size_t)b * 4 + 3) * 128 + t];
    }

    const size_t aoff = ((size_t)b * 1024 + m0 + srow) * 512;
    const size_t boff = ((size_t)b * 128 + srow) * 512;
    float s0part = 0.f;
    f32x4 acc1[4][4] = {}, acc2[4][4] = {};

    float4 fA[4];
    uint4 fB1[2], fB2[2];
    bf16x8 hvR[2];
    auto load_raw = [&](int k0) {
        const float* src = Cc + aoff + k0 + sk;
        #pragma unroll
        for (int i = 0; i < 4; i++) fA[i] = ((const float4*)src)[i];
        fB1[0] = *(const uint4*)(B1g + boff + k0 + sk);
        fB1[1] = *(const uint4*)(B1g + boff + k0 + sk + 8);
        fB2[0] = *(const uint4*)(B2g + boff + k0 + sk);
        fB2[1] = *(const uint4*)(B2g + boff + k0 + sk + 8);
    };
    auto cvt_exp = [&](int k0) {
        const float* fv = (const float*)fA;
        short hv[16];
        #pragma unroll
        for (int j = 0; j < 16; j++) {
            float x = fv[j];
            s0part += x * cws[k0 + sk + j];
            hv[j] = f2h(x);
        }
        hvR[0] = *(bf16x8*)&hv[0]; hvR[1] = *(bf16x8*)&hv[8];
        *(bf16x8*)(c16 + aoff + k0 + sk)     = hvR[0];
        *(bf16x8*)(c16 + aoff + k0 + sk + 8) = hvR[1];
    };

    load_raw(0);
    cvt_exp(0);

    for (int k0 = 0; k0 < 512; k0 += 32) {
        __syncthreads();
        *(bf16x8*)&Ah[srow * LDT + sk]      = hvR[0];
        *(bf16x8*)&Ah[srow * LDT + sk + 8]  = hvR[1];
        *(uint4*)&B1h[srow * LDT + sk]      = fB1[0];
        *(uint4*)&B1h[srow * LDT + sk + 8]  = fB1[1];
        *(uint4*)&B2h[srow * LDT + sk]      = fB2[0];
        *(uint4*)&B2h[srow * LDT + sk + 8]  = fB2[1];
        __syncthreads();
        const bool more = (k0 + 32) < 512;
        if (more) load_raw(k0 + 32);       // loads retire under the MFMA below
        #pragma unroll
        for (int i = 0; i < 4; i++) {
            f16x8 a_ = *(const f16x8*)&Ah[(wr * 64 + i * 16 + fr) * LDT + fg * 8];
            #pragma unroll
            for (int ni = 0; ni < 4; ni++) {
                int br = (wc * 64 + ni * 16 + fr) * LDT + fg * 8;
                f16x8 b1_ = *(const f16x8*)&B1h[br];
                acc1[i][ni] = __builtin_amdgcn_mfma_f32_16x16x32_f16(a_, b1_, acc1[i][ni], 0, 0, 0);
                f16x8 b2_ = *(const f16x8*)&B2h[br];
                acc2[i][ni] = __builtin_amdgcn_mfma_f32_16x16x32_f16(a_, b2_, acc2[i][ni], 0, 0, 0);
            }
        }
        if (more) cvt_exp(k0 + 32);        // cvt + s0 + c16 store also overlapped
    }

    // ---- s0/s1/bias additive terms (sim pipeline only) ----
    s0red[srow][t & 1] = s0part;
    __syncthreads();
    if (t < 128) s0L[t] = s0red[t][0] + s0red[t][1];
    __syncthreads();
    {
        float b0 = biasp[0];
        #pragma unroll
        for (int mi = 0; mi < 4; mi++)
        #pragma unroll
        for (int r = 0; r < 4; r++) {
            float s0r = s0L[wr * 64 + mi * 16 + fg * 4 + r] + b0;
            #pragma unroll
            for (int ni = 0; ni < 4; ni++)
                acc1[mi][ni][r] += s0r + s1L[wc * 64 + ni * 16 + fr];
        }
    }

    bool qmv[4];
    #pragma unroll
    for (int ni = 0; ni < 4; ni++) qmv[ni] = qmsL[wc * 64 + ni * 16 + fr] != 0;
    bool cmb[4][4];
    #pragma unroll
    for (int mi = 0; mi < 4; mi++)
    #pragma unroll
    for (int r = 0; r < 4; r++) cmb[mi][r] = cmsL[wr * 64 + mi * 16 + fg * 4 + r] != 0;

    auto emit = [&](f32x4 (&acc)[4][4], short* __restrict__ Pr,
                    short* __restrict__ Pe, float2* __restrict__ cpart_g) {
        __syncthreads();    // protect red/TT from previous pipeline's readers
        // ---- row softmax ----
        #pragma unroll
        for (int mi = 0; mi < 4; mi++)
        #pragma unroll
        for (int r = 0; r < 4; r++) {
            float m = NEGV;
            #pragma unroll
            for (int ni = 0; ni < 4; ni++) if (qmv[ni]) m = fmaxf(m, acc[mi][ni][r]);
            #pragma unroll
            for (int off = 1; off < 16; off <<= 1) m = fmaxf(m, __shfl_xor(m, off));
            if (fr == 0) red[wc][wr * 64 + mi * 16 + fg * 4 + r] = m;
        }
        __syncthreads();
        if (t < 128) mrowL[t] = fmaxf(red[0][t], red[1][t]);
        __syncthreads();
        #pragma unroll
        for (int mi = 0; mi < 4; mi++)
        #pragma unroll
        for (int r = 0; r < 4; r++) {
            float mr = mrowL[wr * 64 + mi * 16 + fg * 4 + r];
            float s = 0.f;
            #pragma unroll
            for (int ni = 0; ni < 4; ni++) if (qmv[ni]) s += __expf(acc[mi][ni][r] - mr);
            #pragma unroll
            for (int off = 1; off < 16; off <<= 1) s += __shfl_xor(s, off);
            if (fr == 0) red[wc][wr * 64 + mi * 16 + fg * 4 + r] = s;
        }
        __syncthreads();
        if (t < 128) rinvL[t] = 1.f / (red[0][t] + red[1][t]);
        __syncthreads();
        #pragma unroll
        for (int mi = 0; mi < 4; mi++)
        #pragma unroll
        for (int r = 0; r < 4; r++) {
            int rowl = wr * 64 + mi * 16 + fg * 4 + r;
            float mr = mrowL[rowl], iv = rinvL[rowl];
            size_t obase = ((size_t)b * 1024 + m0 + rowl) * 128;
            #pragma unroll
            for (int ni = 0; ni < 4; ni++) {
                float o = qmv[ni] ? __expf(acc[mi][ni][r] - mr) * iv : 0.f;
                Pr[obase + wc * 64 + ni * 16 + fr] = f2h(o);
            }
        }
        // ---- column pass: chunk max, raw exp(v - M_ch) transposed out ----
        float cpart[4];
        #pragma unroll
        for (int ni = 0; ni < 4; ni++) {
            float m = NEGV;
            #pragma unroll
            for (int mi = 0; mi < 4; mi++)
            #pragma unroll
            for (int r = 0; r < 4; r++) if (cmb[mi][r]) m = fmaxf(m, acc[mi][ni][r]);
            m = fmaxf(m, __shfl_xor(m, 16));
            m = fmaxf(m, __shfl_xor(m, 32));
            cpart[ni] = m;
        }
        if (fg == 0) {
            #pragma unroll
            for (int ni = 0; ni < 4; ni++) red[wr][wc * 64 + ni * 16 + fr] = cpart[ni];
        }
        __syncthreads();
        if (t < 128) cmaxL[t] = fmaxf(red[0][t], red[1][t]);
        __syncthreads();
        #pragma unroll
        for (int ni = 0; ni < 4; ni++) {
            const int q = wc * 64 + ni * 16 + fr;
            float cm = cmaxL[q];
            float s = 0.f;
            #pragma unroll
            for (int mi = 0; mi < 4; mi++)
            #pragma unroll
            for (int r = 0; r < 4; r++) {
                int rloc = wr * 64 + mi * 16 + fg * 4 + r;
                float e = cmb[mi][r] ? __expf(acc[mi][ni][r] - cm) : 0.f;
                s += e;
                TT[q * 136 + rloc] = f2h(e);
            }
            s += __shfl_xor(s, 16);
            s += __shfl_xor(s, 32);
            cpart[ni] = s;
        }
        __syncthreads();
        if (fg == 0) {
            #pragma unroll
            for (int ni = 0; ni < 4; ni++) red[wr][wc * 64 + ni * 16 + fr] = cpart[ni];
        }
        __syncthreads();
        {   // coalesced transposed write of the exp-shifted chunk
            const int q2 = t >> 1, half = t & 1;
            short* dst = Pe + ((size_t)b * 128 + q2) * 1024 + m0 + half * 64;
            #pragma unroll
            for (int j = 0; j < 8; j++)
                *(bf16x8*)(dst + j * 8) = *(const bf16x8*)&TT[q2 * 136 + half * 64 + j * 8];
        }
        if (t < 128) cpart_g[((size_t)b * 8 + ch) * 128 + t] = make_float2(cmaxL[t], red[0][t] + red[1][t]);
    };

    emit(acc1, Pr1, Pe1, cp1);
    emit(acc2, Pr2, Pe2, cp2);
}

// ---------------- fused dual K=1024 GEMM (c16 input) with inline column-softmax normalization ----------------
__global__ __launch_bounds__(256)
void k_kgemm2(const short* __restrict__ A1, const short* __restrict__ A2,
              const short* __restrict__ C16, const float2* __restrict__ cpS,
              const float2* __restrict__ cpC, short* __restrict__ Y1T,
              short* __restrict__ Y2T)
{
    __shared__ __align__(16) short Bs[2][64 * LDT];
    __shared__ __align__(16) short TT[64 * 136];
    __shared__ float wtr[2][8][128];
    __shared__ float fin[2][128];
    const int t = threadIdx.x;
    const int b  = (int)(blockIdx.x & 63);
    const int n0 = (int)(blockIdx.x >> 6) * 64;
    const int lane = t & 63;
    const int w  = t >> 6;
    const int wr = w >> 1, wc = w & 1;
    const int fr = lane & 15, fg = lane >> 4;
    const int n4 = (t & 15) * 4, kk2 = (t >> 4) * 2;

    {   // normalization tables
        const int tb = t >> 7, qq = t & 127;
        const float2* cp = tb ? cpC : cpS;
        float2 pc[8];
        #pragma unroll
        for (int c2 = 0; c2 < 8; c2++) pc[c2] = cp[((size_t)b * 8 + c2) * 128 + qq];
        float Mg = NEGV;
        #pragma unroll
        for (int c2 = 0; c2 < 8; c2++) Mg = fmaxf(Mg, pc[c2].x);
        float Sg = 0.f;
        #pragma unroll
        for (int c2 = 0; c2 < 8; c2++) Sg += pc[c2].y * __expf(pc[c2].x - Mg);
        const float clampv = Mg - 60.f;
        float mh[8];
        #pragma unroll
        for (int c2 = 0; c2 < 8; c2++) mh[c2] = fmaxf(pc[c2].x, clampv);
        wtr[tb][0][qq] = 1.f;
        #pragma unroll
        for (int c2 = 1; c2 < 8; c2++) wtr[tb][c2][qq] = __expf(mh[c2 - 1] - mh[c2]);
        fin[tb][qq] = (Sg > 0.f) ? __expf(mh[7] - Mg) / Sg : 0.f;
    }

    f32x4 acc1[4][2] = {}, acc2[4][2] = {};

    auto load_e = [&](int k0, uint2* e) {
        const short* p = C16 + ((size_t)b * 1024 + k0 + kk2) * 512 + n0 + n4;
        e[0] = *(const uint2*)(p);
        e[1] = *(const uint2*)(p + 512);
    };
    auto store_b = [&](const uint2* e, int buf) {
        const unsigned short* r0 = (const unsigned short*)&e[0];
        const unsigned short* r1 = (const unsigned short*)&e[1];
        #pragma unroll
        for (int l = 0; l < 4; l++)
            *(unsigned*)&Bs[buf][(n4 + l) * LDT + kk2] = (unsigned)r0[l] | ((unsigned)r1[l] << 16);
    };

    {
        uint2 e[2];
        load_e(0, e);
        store_b(e, 0);
    }
    __syncthreads();

    for (int k0 = 0; k0 < 1024; k0 += 32) {
        const int cur = (k0 >> 5) & 1;
        const bool more = (k0 + 32) < 1024;
        uint2 e[2];
        if (more) load_e(k0 + 32, e);
        if (k0 && (k0 & 127) == 0) {     // chunk boundary: rescale accumulators
            const int c2 = k0 >> 7;
            #pragma unroll
            for (int mi = 0; mi < 4; mi++)
            #pragma unroll
            for (int r = 0; r < 4; r++) {
                int qq = wr * 64 + mi * 16 + fg * 4 + r;
                float f1 = wtr[0][c2][qq], f2 = wtr[1][c2][qq];
                #pragma unroll
                for (int ni = 0; ni < 2; ni++) {
                    acc1[mi][ni][r] *= f1;
                    acc2[mi][ni][r] *= f2;
                }
            }
        }
        f16x8 a1[4], a2[4], bg[2];
        #pragma unroll
        for (int i = 0; i < 4; i++) {
            size_t arow = (size_t)(b * 128 + wr * 64 + i * 16 + fr) * 1024 + k0 + fg * 8;
            a1[i] = *(const f16x8*)(A1 + arow);
            a2[i] = *(const f16x8*)(A2 + arow);
        }
        #pragma unroll
        for (int i = 0; i < 2; i++)
            bg[i] = *(const f16x8*)&Bs[cur][(wc * 32 + i * 16 + fr) * LDT + fg * 8];
        #pragma unroll
        for (int mi = 0; mi < 4; mi++)
        #pragma unroll
        for (int ni = 0; ni < 2; ni++) {
            acc1[mi][ni] = __builtin_amdgcn_mfma_f32_16x16x32_f16(a1[mi], bg[ni], acc1[mi][ni], 0, 0, 0);
            acc2[mi][ni] = __builtin_amdgcn_mfma_f32_16x16x32_f16(a2[mi], bg[ni], acc2[mi][ni], 0, 0, 0);
        }
        if (more) store_b(e, cur ^ 1);
        __syncthreads();
    }

    // transpose-bounce both outputs -> coalesced [B,512,128] fp16 (h-permuted rows), final scale
    const int n_l = t >> 2, qu = t & 3;
    const int nm = p64(n_l);
    #pragma unroll
    for (int mi = 0; mi < 4; mi++)
    #pragma unroll
    for (int r = 0; r < 4; r++) {
        int ml = wr * 64 + mi * 16 + fg * 4 + r;
        float fs = fin[0][ml];
        #pragma unroll
        for (int ni = 0; ni < 2; ni++)
            TT[(wc * 32 + ni * 16 + fr) * 136 + ml] = f2h(acc1[mi][ni][r] * fs);
    }
    __syncthreads();
    {
        short* dst = Y1T + ((size_t)b * 512 + n0 + nm) * 128 + qu * 32;
        #pragma unroll
        for (int j = 0; j < 4; j++)
            *(bf16x8*)(dst + j * 8) = *(const bf16x8*)&TT[n_l * 136 + qu * 32 + j * 8];
    }
    __syncthreads();
    #pragma unroll
    for (int mi = 0; mi < 4; mi++)
    #pragma unroll
    for (int r = 0; r < 4; r++) {
        int ml = wr * 64 + mi * 16 + fg * 4 + r;
        float fs = fin[1][ml];
        #pragma unroll
        for (int ni = 0; ni < 2; ni++)
            TT[(wc * 32 + ni * 16 + fr) * 136 + ml] = f2h(acc2[mi][ni][r] * fs);
    }
    __syncthreads();
    {
        short* dst = Y2T + ((size_t)b * 512 + n0 + nm) * 128 + qu * 32;
        #pragma unroll
        for (int j = 0; j < 4; j++)
            *(bf16x8*)(dst + j * 8) = *(const bf16x8*)&TT[n_l * 136 + qu * 32 + j * 8];
    }
}

// ---------------- slim epilogue GEMMs (K=128, fp16), 128^2 tiles, ONE accumulator each ----------------
// PART 0: av = P@qT   -> writes c, a, c*a   (channels 0, 512, 1024)
// PART 1: bv = P@binT -> writes c*b         (channel 1536)
// PART 2: sc1@bcoT    -> writes scoat3      (channel 2048)
// PART 3: sc1@qpT     -> writes acoat       (channel 2560)
template<int PART>
__global__ __launch_bounds__(256)
void k_epi1(const short* __restrict__ Pm, const short* __restrict__ BT,
            const short* __restrict__ C16, float* __restrict__ out)
{
    const int t = threadIdx.x;
    const int hb = (int)(blockIdx.x & 3);
    const int mb = (int)((blockIdx.x >> 2) & 7);
    const int b  = (int)(blockIdx.x >> 5);
    const int m0 = mb * 128, h0 = hb * 128;
    const int lane = t & 63;
    const int wr = (t >> 7) & 1, wc = (t >> 6) & 1;
    const int fr = lane & 15, fg = lane >> 4;
    f32x4 acc[4][4] = {};
    const short* Abase = Pm + ((size_t)b * 1024 + m0) * 128;
    const short* Bbase = BT + ((size_t)b * 512 + h0) * 128;
    #pragma unroll
    for (int kk = 0; kk < 4; kk++) {
        const int k0 = kk * 32;
        f16x8 af[4], bf_[4];
        #pragma unroll
        for (int i = 0; i < 4; i++) {
            af[i]  = *(const f16x8*)(Abase + (size_t)(wr * 64 + i * 16 + fr) * 128 + k0 + fg * 8);
            bf_[i] = *(const f16x8*)(Bbase + (size_t)(wc * 64 + i * 16 + fr) * 128 + k0 + fg * 8);
        }
        #pragma unroll
        for (int mi = 0; mi < 4; mi++)
        #pragma unroll
        for (int ni = 0; ni < 4; ni++)
            acc[mi][ni] = __builtin_amdgcn_mfma_f32_16x16x32_f16(af[mi], bf_[ni], acc[mi][ni], 0, 0, 0);
    }
    const size_t crow_base = (size_t)b * 1024 + m0;
    const int colb = wc * 64 + fr * 4;       // logical column base (4 consecutive, via h-permutation)
    #pragma unroll
    for (int mi = 0; mi < 4; mi++)
    #pragma unroll
    for (int r = 0; r < 4; r++) {
        int rowl = wr * 64 + mi * 16 + fg * 4 + r;
        size_t obase = (crow_base + rowl) * 3072 + h0 + colb;
        float4 v;
        v.x = acc[mi][0][r]; v.y = acc[mi][1][r]; v.z = acc[mi][2][r]; v.w = acc[mi][3][r];
        if (PART == 0) {
            f16x4 cv4 = *(const f16x4*)(C16 + (crow_base + rowl) * 512 + h0 + colb);
            float4 cv; cv.x = (float)cv4[0]; cv.y = (float)cv4[1]; cv.z = (float)cv4[2]; cv.w = (float)cv4[3];
            *(float4*)(out + obase) = cv;
            *(float4*)(out + obase + 512) = v;
            float4 ca; ca.x = cv.x * v.x; ca.y = cv.y * v.y; ca.z = cv.z * v.z; ca.w = cv.w * v.w;
            *(float4*)(out + obase + 1024) = ca;
        } else if (PART == 1) {
            f16x4 cv4 = *(const f16x4*)(C16 + (crow_base + rowl) * 512 + h0 + colb);
            float4 cb;
            cb.x = (float)cv4[0] * v.x; cb.y = (float)cv4[1] * v.y;
            cb.z = (float)cv4[2] * v.z; cb.w = (float)cv4[3] * v.w;
            *(float4*)(out + obase + 1536) = cb;
        } else if (PART == 2) {
            *(float4*)(out + obase + 2048) = v;
        } else {
            *(float4*)(out + obase + 2560) = v;
        }
    }
}

// ---------------- host launcher ----------------
extern "C" void kernel_launch(void* const* d_in, const int* in_sizes, int n_in,
                              void* d_out, int out_size, void* d_ws, size_t ws_size,
                              hipStream_t stream)
{
    const float* c     = (const float*)d_in[0];
    const float* q     = (const float*)d_in[1];
    const int*   cmask = (const int*)d_in[2];
    const int*   qmask = (const int*)d_in[3];
    const float* cwv   = (const float*)d_in[4];
    const float* qwv   = (const float*)d_in[5];
    const float* cqw   = (const float*)d_in[6];
    const float* bias  = (const float*)d_in[7];
    const float* W1    = (const float*)d_in[8];
    const float* b1    = (const float*)d_in[9];
    const float* W2    = (const float*)d_in[10];
    const float* b2    = (const float*)d_in[11];
    float* out = (float*)d_out;

    char* ws = (char*)d_ws;
    size_t off = 0;
    auto alloc = [&](size_t bytes) -> char* {
        char* p = ws + off;
        off = (off + bytes + 255) & ~(size_t)255;
        return p;
    };
    short* w1th = (short*)alloc(512 * 512 * 2);
    short* w1tl = (short*)alloc(512 * 512 * 2);
    short* w2th = (short*)alloc(512 * 512 * 2);
    short* w2tl = (short*)alloc(512 * 512 * 2);
    float* s1p  = (float*)alloc(64 * 4 * 128 * 4);
    short* q_cq = (short*)alloc((size_t)64 * 128 * 512 * 2);
    short* qT   = (short*)alloc((size_t)64 * 512 * 128 * 2);
    float* z1   = (float*)alloc((size_t)8192 * 512 * 4);     // layer-1 act; reused for binT/bcoT
    short* qp_f = (short*)alloc((size_t)8192 * 512 * 2);     // fp16 qp
    short* qpT  = (short*)alloc((size_t)64 * 512 * 128 * 2);
    short* c16  = (short*)alloc((size_t)64 * 1024 * 512 * 2);  // fp16 c (exported by k_att_dual)
    float2* colpartS = (float2*)alloc((size_t)64 * 8 * 128 * 8);
    float2* colpartC = (float2*)alloc((size_t)64 * 8 * 128 * 8);
    short* s1s  = (short*)alloc((size_t)64 * 1024 * 128 * 2);
    short* s2sT = (short*)alloc((size_t)64 * 128 * 1024 * 2);  // raw per-chunk exp (fp16)
    short* sc1  = (short*)alloc((size_t)64 * 1024 * 128 * 2);
    short* sc2T = (short*)alloc((size_t)64 * 128 * 1024 * 2);  // raw per-chunk exp (fp16)
    short* binT = (short*)z1;
    short* bcoT = ((short*)z1) + (size_t)64 * 512 * 128;

    k_prep_w<<<2048, 256, 0, stream>>>(W1, W2, w1th, w1tl, w2th, w2tl);
    k_prep_q<<<256, 256, 0, stream>>>(q, qwv, cqw, q_cq, qT, s1p);
    k_linear<false><<<256, 256, 0, stream>>>(q, w1th, w1tl, b1, z1, nullptr, nullptr);
    k_linear<true><<<256, 256, 0, stream>>>(z1, w2th, w2tl, b2, nullptr, qp_f, qpT);

    // merged logits pipelines: one c read, both GEMMs, c16 export (reg-prefetch K-loop)
    k_att_dual<<<512, 256, 0, stream>>>(
        c, q_cq, qp_f, cwv, s1p, bias, qmask, cmask, c16,
        s1s, s2sT, colpartS, sc1, sc2T, colpartC);

    // fused dual K=1024 GEMM (fp16 c16 input) with inline column-softmax normalization
    k_kgemm2<<<512, 256, 0, stream>>>(s2sT, sc2T, c16, colpartS, colpartC, binT, bcoT);

    // slim output epilogues: one accumulator per kernel -> low VGPR, higher occupancy
    k_epi1<0><<<2048, 256, 0, stream>>>(s1s, qT,   c16, out);
    k_epi1<2><<<2048, 256, 0, stream>>>(sc1, bcoT, nullptr, out);
    k_epi1<1><<<2048, 256, 0, stream>>>(s1s, binT, c16, out);
    k_epi1<3><<<2048, 256, 0, stream>>>(sc1, qpT,  nullptr, out);
}

// Round 12
// 570.157 us; speedup vs baseline: 1.1023x; 1.0973x over previous
//
#include <hip/hip_runtime.h>
#include <cstdint>
#include <cstddef>

typedef short    bf16x8 __attribute__((ext_vector_type(8)));
typedef _Float16 f16x8  __attribute__((ext_vector_type(8)));
typedef _Float16 f16x4  __attribute__((ext_vector_type(4)));
typedef float    f32x4  __attribute__((ext_vector_type(4)));

#define NEGV (-1e30f)
#define LDT 40   // padded LDS row pitch (shorts) = 80B: 16B-aligned, 2-way-conflict max (free)

__device__ __forceinline__ short f2bf(float x){
    union { float f; unsigned u; } v; v.f = x;
    return (short)((v.u + 0x7fffu + ((v.u >> 16) & 1u)) >> 16);
}
__device__ __forceinline__ float bf2f(short h){
    union { float f; unsigned u; } v; v.u = ((unsigned)(unsigned short)h) << 16; return v.f;
}
__device__ __forceinline__ short f2h(float x){
    _Float16 h = (_Float16)x;
    union { _Float16 h; unsigned short u; } v; v.h = h;
    return (short)v.u;
}
__device__ __forceinline__ unsigned packh(float a, float b){
    return (unsigned)(unsigned short)f2h(a) | ((unsigned)(unsigned short)f2h(b) << 16);
}
// memory row (within a 64-row group) holding logical column h:
// epi's B-fragment load at row ni*16+fr then yields logical col fr*4+ni (consecutive per thread)
__device__ __forceinline__ int p64(int x){ return ((x & 3) << 4) | (x >> 2); }

// ---------------- prep: W1,W2 -> transposed bf16 hi/lo (MLP stays split-bf16) ----------------
__global__ __launch_bounds__(256)
void k_prep_w(const float* __restrict__ W1, const float* __restrict__ W2,
              short* __restrict__ W1Th, short* __restrict__ W1Tl,
              short* __restrict__ W2Th, short* __restrict__ W2Tl)
{
    int idx = blockIdx.x * 256 + threadIdx.x;
    int w = idx >> 18;
    int e = idx & ((1 << 18) - 1);
    int n = e & 511, k = e >> 9;
    const float* W = w ? W2 : W1;
    float x = W[k * 512 + n];
    short hi = f2bf(x);
    short lo = f2bf(x - bf2f(hi));
    size_t o = (size_t)n * 512 + k;
    if (w) { W2Th[o] = hi; W2Tl[o] = lo; } else { W1Th[o] = hi; W1Tl[o] = lo; }
}

// ---------------- prep q: qT (fp16, transposed, h-permuted), q_cq = f16(q*cqw), s1 partials ----------------
__global__ __launch_bounds__(256)
void k_prep_q(const float* __restrict__ q, const float* __restrict__ qwv,
              const float* __restrict__ cqw, short* __restrict__ q_cq,
              short* __restrict__ qT, float* __restrict__ s1p)
{
    __shared__ short TT[128 * 136];
    __shared__ float qws[128], cqs[128];
    const int t = threadIdx.x;
    const int b = (int)(blockIdx.x >> 2), hb = (int)(blockIdx.x & 3), h0 = hb * 128;
    if (t < 128) { qws[t] = qwv[h0 + t]; cqs[t] = cqw[h0 + t]; }
    __syncthreads();
    #pragma unroll
    for (int it = 0; it < 16; it++) {
        int idx = it * 256 + t;
        int m = idx >> 5, c4 = (idx & 31) * 4;
        float4 v = *(const float4*)(q + ((size_t)b * 128 + m) * 512 + h0 + c4);
        TT[(c4 + 0) * 136 + m] = f2h(v.x);
        TT[(c4 + 1) * 136 + m] = f2h(v.y);
        TT[(c4 + 2) * 136 + m] = f2h(v.z);
        TT[(c4 + 3) * 136 + m] = f2h(v.w);
        uint2 d;
        d.x = packh(v.x * cqs[c4],     v.y * cqs[c4 + 1]);
        d.y = packh(v.z * cqs[c4 + 2], v.w * cqs[c4 + 3]);
        *(uint2*)(q_cq + ((size_t)b * 128 + m) * 512 + h0 + c4) = d;
        float dot = v.x * qws[c4] + v.y * qws[c4 + 1] + v.z * qws[c4 + 2] + v.w * qws[c4 + 3];
        #pragma unroll
        for (int off = 1; off < 32; off <<= 1) dot += __shfl_xor(dot, off);
        if ((t & 31) == 0) s1p[((size_t)b * 4 + hb) * 128 + m] = dot;
    }
    __syncthreads();
    const int h = t >> 1, half = t & 1;
    const int hm = (h & 64) + p64(h & 63);   // permuted destination row
    short* dst = qT + ((size_t)b * 512 + h0 + hm) * 128 + half * 64;
    #pragma unroll
    for (int j = 0; j < 8; j++)
        *(bf16x8*)(dst + j * 8) = *(const bf16x8*)&TT[h * 136 + half * 64 + j * 8];
}

// ---------------- split-bf16 linear; WT variant writes fp16 copy + transposed (h-permuted) fp16 copy ----------------
template<bool WT>
__global__ __launch_bounds__(256)
void k_linear(const float* __restrict__ X, const short* __restrict__ WTh,
              const short* __restrict__ WTl, const float* __restrict__ bias,
              float* __restrict__ Y, short* __restrict__ Yf,
              short* __restrict__ YT)
{
    __shared__ __align__(16) short SMEM[4 * 128 * LDT];
    short* Ah = SMEM;
    short* Al = SMEM + 128 * LDT;
    short* Bh = SMEM + 2 * 128 * LDT;
    short* Bl = SMEM + 3 * 128 * LDT;
    const int t = threadIdx.x;
    const int m0 = (int)(blockIdx.x >> 2) * 128;
    const int n0 = (int)(blockIdx.x & 3) * 128;
    const int lane = t & 63;
    const int wr = (t >> 7) & 1, wc = (t >> 6) & 1;
    const int fr = lane & 15, fg = lane >> 4;
    const int srow = t >> 1, sk = (t & 1) * 16;

    f32x4 acc[4][4] = {};

    for (int k0 = 0; k0 < 512; k0 += 32) {
        __syncthreads();
        {
            const float* src = X + (size_t)(m0 + srow) * 512 + k0 + sk;
            float4 f[4];
            #pragma unroll
            for (int i = 0; i < 4; i++) f[i] = ((const float4*)src)[i];
            const float* fv = (const float*)f;
            short hi[16], lo[16];
            #pragma unroll
            for (int j = 0; j < 16; j++) {
                float x = fv[j];
                short h = f2bf(x);
                hi[j] = h; lo[j] = f2bf(x - bf2f(h));
            }
            #pragma unroll
            for (int j = 0; j < 2; j++) {
                *(bf16x8*)&Ah[srow * LDT + sk + j * 8] = *(bf16x8*)&hi[j * 8];
                *(bf16x8*)&Al[srow * LDT + sk + j * 8] = *(bf16x8*)&lo[j * 8];
            }
        }
        {
            const short* sh = WTh + (size_t)(n0 + srow) * 512 + k0 + sk;
            const short* sl = WTl + (size_t)(n0 + srow) * 512 + k0 + sk;
            #pragma unroll
            for (int j = 0; j < 2; j++) {
                *(bf16x8*)&Bh[srow * LDT + sk + j * 8] = ((const bf16x8*)sh)[j];
                *(bf16x8*)&Bl[srow * LDT + sk + j * 8] = ((const bf16x8*)sl)[j];
            }
        }
        __syncthreads();
        bf16x8 a_h[4], a_l[4], b_h[4], b_l[4];
        #pragma unroll
        for (int i = 0; i < 4; i++) {
            int ar = (wr * 64 + i * 16 + fr) * LDT + fg * 8;
            int br = (wc * 64 + i * 16 + fr) * LDT + fg * 8;
            a_h[i] = *(const bf16x8*)&Ah[ar];
            a_l[i] = *(const bf16x8*)&Al[ar];
            b_h[i] = *(const bf16x8*)&Bh[br];
            b_l[i] = *(const bf16x8*)&Bl[br];
        }
        #pragma unroll
        for (int mi = 0; mi < 4; mi++)
        #pragma unroll
        for (int ni = 0; ni < 4; ni++) {
            acc[mi][ni] = __builtin_amdgcn_mfma_f32_16x16x32_bf16(a_h[mi], b_h[ni], acc[mi][ni], 0, 0, 0);
            acc[mi][ni] = __builtin_amdgcn_mfma_f32_16x16x32_bf16(a_h[mi], b_l[ni], acc[mi][ni], 0, 0, 0);
            acc[mi][ni] = __builtin_amdgcn_mfma_f32_16x16x32_bf16(a_l[mi], b_h[ni], acc[mi][ni], 0, 0, 0);
        }
    }
    float bv[4];
    #pragma unroll
    for (int ni = 0; ni < 4; ni++) bv[ni] = bias[n0 + wc * 64 + ni * 16 + fr];

    if (!WT) {
        #pragma unroll
        for (int mi = 0; mi < 4; mi++)
        #pragma unroll
        for (int r = 0; r < 4; r++) {
            int row = m0 + wr * 64 + mi * 16 + fg * 4 + r;
            #pragma unroll
            for (int ni = 0; ni < 4; ni++)
                Y[(size_t)row * 512 + n0 + wc * 64 + ni * 16 + fr] =
                    fmaxf(acc[mi][ni][r] + bv[ni], 0.f);
        }
    } else {
        #pragma unroll
        for (int mi = 0; mi < 4; mi++)
        #pragma unroll
        for (int r = 0; r < 4; r++) {
            int row = m0 + wr * 64 + mi * 16 + fg * 4 + r;
            #pragma unroll
            for (int ni = 0; ni < 4; ni++) {
                float v = fmaxf(acc[mi][ni][r] + bv[ni], 0.f);
                size_t o = (size_t)row * 512 + n0 + wc * 64 + ni * 16 + fr;
                Yf[o] = f2h(v);     // fp16 copy for the scoat logits GEMM
            }
        }
        __syncthreads();
        short* TT = SMEM;
        #pragma unroll
        for (int mi = 0; mi < 4; mi++)
        #pragma unroll
        for (int r = 0; r < 4; r++) {
            int ml = wr * 64 + mi * 16 + fg * 4 + r;
            #pragma unroll
            for (int ni = 0; ni < 4; ni++)
                TT[(wc * 64 + ni * 16 + fr) * 136 + ml] =
                    f2h(fmaxf(acc[mi][ni][r] + bv[ni], 0.f));
        }
        __syncthreads();
        const int n = t >> 1, half = t & 1;
        const int nm = (n & 64) + p64(n & 63);   // permuted destination row
        short* dst = YT + ((size_t)(m0 >> 7) * 512 + n0 + nm) * 128 + half * 64;
        #pragma unroll
        for (int j = 0; j < 8; j++)
            *(bf16x8*)(dst + j * 8) = *(const bf16x8*)&TT[n * 136 + half * 64 + j * 8];
    }
}

// ---------------- DUAL logits GEMM: one c read -> both sim & scoat pipelines ----------------
// A = c fp32 -> fp16 on the fly (also exported to c16 for downstream consumers).
// B1 = q_cq (sim), B2 = qp (scoat). Dual f32 accumulators; sequential dual-softmax epilogues.
__global__ __launch_bounds__(256, 2)
void k_att_dual(const float* __restrict__ Cc, const short* __restrict__ B1g,
                const short* __restrict__ B2g, const float* __restrict__ cwv,
                const float* __restrict__ s1pg, const float* __restrict__ biasp,
                const int* __restrict__ qmask, const int* __restrict__ cmask,
                short* __restrict__ c16,
                short* __restrict__ Pr1, short* __restrict__ Pe1, float2* __restrict__ cp1,
                short* __restrict__ Pr2, short* __restrict__ Pe2, float2* __restrict__ cp2)
{
    __shared__ __align__(16) short SM[128 * 136];   // staging 3*128*LDT=30720B | bounce 34816B
    short* Ah  = SM;
    short* B1h = SM + 128 * LDT;
    short* B2h = SM + 2 * 128 * LDT;
    short* TT  = SM;
    __shared__ float red[2][128];
    __shared__ float mrowL[128], rinvL[128], cmaxL[128];
    __shared__ float cws[512];
    __shared__ float s0red[128][2];
    __shared__ float s0L[128], s1L[128];
    __shared__ int qmsL[128], cmsL[128];

    const int t = threadIdx.x;
    const int b  = (int)(blockIdx.x & 63);      // 8 chunks of b land on one XCD
    const int ch = (int)(blockIdx.x >> 6);
    const int m0 = ch * 128;
    const int lane = t & 63;
    const int wr = (t >> 7) & 1, wc = (t >> 6) & 1;
    const int fr = lane & 15, fg = lane >> 4;
    const int srow = t >> 1, sk = (t & 1) * 16;

    cws[t] = cwv[t]; cws[t + 256] = cwv[t + 256];
    if (t < 128) {
        qmsL[t] = qmask[b * 128 + t];
        cmsL[t] = cmask[b * 1024 + m0 + t];
        s1L[t] = s1pg[((size_t)b * 4 + 0) * 128 + t] + s1pg[((size_t)b * 4 + 1) * 128 + t]
               + s1pg[((size_t)b * 4 + 2) * 128 + t] + s1pg[((size_t)b * 4 + 3) * 128 + t];
    }

    const size_t aoff = ((size_t)b * 1024 + m0 + srow) * 512;
    const size_t boff = ((size_t)b * 128 + srow) * 512;
    float s0part = 0.f;
    f32x4 acc1[4][4] = {}, acc2[4][4] = {};

    for (int k0 = 0; k0 < 512; k0 += 32) {
        __syncthreads();
        {   // A from c fp32 -> fp16; s0 dot; export c16
            const float* src = Cc + aoff + k0 + sk;
            float4 f[4];
            #pragma unroll
            for (int i = 0; i < 4; i++) f[i] = ((const float4*)src)[i];
            const float* fv = (const float*)f;
            short hv[16];
            #pragma unroll
            for (int j = 0; j < 16; j++) {
                float x = fv[j];
                s0part += x * cws[k0 + sk + j];
                hv[j] = f2h(x);
            }
            #pragma unroll
            for (int j = 0; j < 2; j++) {
                *(bf16x8*)&Ah[srow * LDT + sk + j * 8] = *(bf16x8*)&hv[j * 8];
                *(bf16x8*)(c16 + aoff + k0 + sk + j * 8) = *(bf16x8*)&hv[j * 8];
            }
        }
        {   // B1/B2: pure 16-bit copies
            *(uint4*)&B1h[srow * LDT + sk]     = *(const uint4*)(B1g + boff + k0 + sk);
            *(uint4*)&B1h[srow * LDT + sk + 8] = *(const uint4*)(B1g + boff + k0 + sk + 8);
            *(uint4*)&B2h[srow * LDT + sk]     = *(const uint4*)(B2g + boff + k0 + sk);
            *(uint4*)&B2h[srow * LDT + sk + 8] = *(const uint4*)(B2g + boff + k0 + sk + 8);
        }
        __syncthreads();
        #pragma unroll
        for (int i = 0; i < 4; i++) {
            f16x8 a_ = *(const f16x8*)&Ah[(wr * 64 + i * 16 + fr) * LDT + fg * 8];
            #pragma unroll
            for (int ni = 0; ni < 4; ni++) {
                int br = (wc * 64 + ni * 16 + fr) * LDT + fg * 8;
                f16x8 b1_ = *(const f16x8*)&B1h[br];
                acc1[i][ni] = __builtin_amdgcn_mfma_f32_16x16x32_f16(a_, b1_, acc1[i][ni], 0, 0, 0);
                f16x8 b2_ = *(const f16x8*)&B2h[br];
                acc2[i][ni] = __builtin_amdgcn_mfma_f32_16x16x32_f16(a_, b2_, acc2[i][ni], 0, 0, 0);
            }
        }
    }

    // ---- s0/s1/bias additive terms (sim pipeline only) ----
    s0red[srow][t & 1] = s0part;
    __syncthreads();
    if (t < 128) s0L[t] = s0red[t][0] + s0red[t][1];
    __syncthreads();
    {
        float b0 = biasp[0];
        #pragma unroll
        for (int mi = 0; mi < 4; mi++)
        #pragma unroll
        for (int r = 0; r < 4; r++) {
            float s0r = s0L[wr * 64 + mi * 16 + fg * 4 + r] + b0;
            #pragma unroll
            for (int ni = 0; ni < 4; ni++)
                acc1[mi][ni][r] += s0r + s1L[wc * 64 + ni * 16 + fr];
        }
    }

    bool qmv[4];
    #pragma unroll
    for (int ni = 0; ni < 4; ni++) qmv[ni] = qmsL[wc * 64 + ni * 16 + fr] != 0;
    bool cmb[4][4];
    #pragma unroll
    for (int mi = 0; mi < 4; mi++)
    #pragma unroll
    for (int r = 0; r < 4; r++) cmb[mi][r] = cmsL[wr * 64 + mi * 16 + fg * 4 + r] != 0;

    auto emit = [&](f32x4 (&acc)[4][4], short* __restrict__ Pr,
                    short* __restrict__ Pe, float2* __restrict__ cpart_g) {
        __syncthreads();    // protect red/TT from previous pipeline's readers
        // ---- row softmax ----
        #pragma unroll
        for (int mi = 0; mi < 4; mi++)
        #pragma unroll
        for (int r = 0; r < 4; r++) {
            float m = NEGV;
            #pragma unroll
            for (int ni = 0; ni < 4; ni++) if (qmv[ni]) m = fmaxf(m, acc[mi][ni][r]);
            #pragma unroll
            for (int off = 1; off < 16; off <<= 1) m = fmaxf(m, __shfl_xor(m, off));
            if (fr == 0) red[wc][wr * 64 + mi * 16 + fg * 4 + r] = m;
        }
        __syncthreads();
        if (t < 128) mrowL[t] = fmaxf(red[0][t], red[1][t]);
        __syncthreads();
        #pragma unroll
        for (int mi = 0; mi < 4; mi++)
        #pragma unroll
        for (int r = 0; r < 4; r++) {
            float mr = mrowL[wr * 64 + mi * 16 + fg * 4 + r];
            float s = 0.f;
            #pragma unroll
            for (int ni = 0; ni < 4; ni++) if (qmv[ni]) s += __expf(acc[mi][ni][r] - mr);
            #pragma unroll
            for (int off = 1; off < 16; off <<= 1) s += __shfl_xor(s, off);
            if (fr == 0) red[wc][wr * 64 + mi * 16 + fg * 4 + r] = s;
        }
        __syncthreads();
        if (t < 128) rinvL[t] = 1.f / (red[0][t] + red[1][t]);
        __syncthreads();
        #pragma unroll
        for (int mi = 0; mi < 4; mi++)
        #pragma unroll
        for (int r = 0; r < 4; r++) {
            int rowl = wr * 64 + mi * 16 + fg * 4 + r;
            float mr = mrowL[rowl], iv = rinvL[rowl];
            size_t obase = ((size_t)b * 1024 + m0 + rowl) * 128;
            #pragma unroll
            for (int ni = 0; ni < 4; ni++) {
                float o = qmv[ni] ? __expf(acc[mi][ni][r] - mr) * iv : 0.f;
                Pr[obase + wc * 64 + ni * 16 + fr] = f2h(o);
            }
        }
        // ---- column pass: chunk max, raw exp(v - M_ch) transposed out ----
        float cpart[4];
        #pragma unroll
        for (int ni = 0; ni < 4; ni++) {
            float m = NEGV;
            #pragma unroll
            for (int mi = 0; mi < 4; mi++)
            #pragma unroll
            for (int r = 0; r < 4; r++) if (cmb[mi][r]) m = fmaxf(m, acc[mi][ni][r]);
            m = fmaxf(m, __shfl_xor(m, 16));
            m = fmaxf(m, __shfl_xor(m, 32));
            cpart[ni] = m;
        }
        if (fg == 0) {
            #pragma unroll
            for (int ni = 0; ni < 4; ni++) red[wr][wc * 64 + ni * 16 + fr] = cpart[ni];
        }
        __syncthreads();
        if (t < 128) cmaxL[t] = fmaxf(red[0][t], red[1][t]);
        __syncthreads();
        #pragma unroll
        for (int ni = 0; ni < 4; ni++) {
            const int q = wc * 64 + ni * 16 + fr;
            float cm = cmaxL[q];
            float s = 0.f;
            #pragma unroll
            for (int mi = 0; mi < 4; mi++)
            #pragma unroll
            for (int r = 0; r < 4; r++) {
                int rloc = wr * 64 + mi * 16 + fg * 4 + r;
                float e = cmb[mi][r] ? __expf(acc[mi][ni][r] - cm) : 0.f;
                s += e;
                TT[q * 136 + rloc] = f2h(e);
            }
            s += __shfl_xor(s, 16);
            s += __shfl_xor(s, 32);
            cpart[ni] = s;
        }
        __syncthreads();
        if (fg == 0) {
            #pragma unroll
            for (int ni = 0; ni < 4; ni++) red[wr][wc * 64 + ni * 16 + fr] = cpart[ni];
        }
        __syncthreads();
        {   // coalesced transposed write of the exp-shifted chunk
            const int q2 = t >> 1, half = t & 1;
            short* dst = Pe + ((size_t)b * 128 + q2) * 1024 + m0 + half * 64;
            #pragma unroll
            for (int j = 0; j < 8; j++)
                *(bf16x8*)(dst + j * 8) = *(const bf16x8*)&TT[q2 * 136 + half * 64 + j * 8];
        }
        if (t < 128) cpart_g[((size_t)b * 8 + ch) * 128 + t] = make_float2(cmaxL[t], red[0][t] + red[1][t]);
    };

    emit(acc1, Pr1, Pe1, cp1);
    emit(acc2, Pr2, Pe2, cp2);
}

// ---------------- fused dual K=1024 GEMM (c16 input) with inline column-softmax normalization ----------------
__global__ __launch_bounds__(256)
void k_kgemm2(const short* __restrict__ A1, const short* __restrict__ A2,
              const short* __restrict__ C16, const float2* __restrict__ cpS,
              const float2* __restrict__ cpC, short* __restrict__ Y1T,
              short* __restrict__ Y2T)
{
    __shared__ __align__(16) short Bs[2][64 * LDT];
    __shared__ __align__(16) short TT[64 * 136];
    __shared__ float wtr[2][8][128];
    __shared__ float fin[2][128];
    const int t = threadIdx.x;
    const int b  = (int)(blockIdx.x & 63);
    const int n0 = (int)(blockIdx.x >> 6) * 64;
    const int lane = t & 63;
    const int w  = t >> 6;
    const int wr = w >> 1, wc = w & 1;
    const int fr = lane & 15, fg = lane >> 4;
    const int n4 = (t & 15) * 4, kk2 = (t >> 4) * 2;

    {   // normalization tables
        const int tb = t >> 7, qq = t & 127;
        const float2* cp = tb ? cpC : cpS;
        float2 pc[8];
        #pragma unroll
        for (int c2 = 0; c2 < 8; c2++) pc[c2] = cp[((size_t)b * 8 + c2) * 128 + qq];
        float Mg = NEGV;
        #pragma unroll
        for (int c2 = 0; c2 < 8; c2++) Mg = fmaxf(Mg, pc[c2].x);
        float Sg = 0.f;
        #pragma unroll
        for (int c2 = 0; c2 < 8; c2++) Sg += pc[c2].y * __expf(pc[c2].x - Mg);
        const float clampv = Mg - 60.f;
        float mh[8];
        #pragma unroll
        for (int c2 = 0; c2 < 8; c2++) mh[c2] = fmaxf(pc[c2].x, clampv);
        wtr[tb][0][qq] = 1.f;
        #pragma unroll
        for (int c2 = 1; c2 < 8; c2++) wtr[tb][c2][qq] = __expf(mh[c2 - 1] - mh[c2]);
        fin[tb][qq] = (Sg > 0.f) ? __expf(mh[7] - Mg) / Sg : 0.f;
    }

    f32x4 acc1[4][2] = {}, acc2[4][2] = {};

    auto load_e = [&](int k0, uint2* e) {
        const short* p = C16 + ((size_t)b * 1024 + k0 + kk2) * 512 + n0 + n4;
        e[0] = *(const uint2*)(p);
        e[1] = *(const uint2*)(p + 512);
    };
    auto store_b = [&](const uint2* e, int buf) {
        const unsigned short* r0 = (const unsigned short*)&e[0];
        const unsigned short* r1 = (const unsigned short*)&e[1];
        #pragma unroll
        for (int l = 0; l < 4; l++)
            *(unsigned*)&Bs[buf][(n4 + l) * LDT + kk2] = (unsigned)r0[l] | ((unsigned)r1[l] << 16);
    };

    {
        uint2 e[2];
        load_e(0, e);
        store_b(e, 0);
    }
    __syncthreads();

    for (int k0 = 0; k0 < 1024; k0 += 32) {
        const int cur = (k0 >> 5) & 1;
        const bool more = (k0 + 32) < 1024;
        uint2 e[2];
        if (more) load_e(k0 + 32, e);
        if (k0 && (k0 & 127) == 0) {     // chunk boundary: rescale accumulators
            const int c2 = k0 >> 7;
            #pragma unroll
            for (int mi = 0; mi < 4; mi++)
            #pragma unroll
            for (int r = 0; r < 4; r++) {
                int qq = wr * 64 + mi * 16 + fg * 4 + r;
                float f1 = wtr[0][c2][qq], f2 = wtr[1][c2][qq];
                #pragma unroll
                for (int ni = 0; ni < 2; ni++) {
                    acc1[mi][ni][r] *= f1;
                    acc2[mi][ni][r] *= f2;
                }
            }
        }
        f16x8 a1[4], a2[4], bg[2];
        #pragma unroll
        for (int i = 0; i < 4; i++) {
            size_t arow = (size_t)(b * 128 + wr * 64 + i * 16 + fr) * 1024 + k0 + fg * 8;
            a1[i] = *(const f16x8*)(A1 + arow);
            a2[i] = *(const f16x8*)(A2 + arow);
        }
        #pragma unroll
        for (int i = 0; i < 2; i++)
            bg[i] = *(const f16x8*)&Bs[cur][(wc * 32 + i * 16 + fr) * LDT + fg * 8];
        #pragma unroll
        for (int mi = 0; mi < 4; mi++)
        #pragma unroll
        for (int ni = 0; ni < 2; ni++) {
            acc1[mi][ni] = __builtin_amdgcn_mfma_f32_16x16x32_f16(a1[mi], bg[ni], acc1[mi][ni], 0, 0, 0);
            acc2[mi][ni] = __builtin_amdgcn_mfma_f32_16x16x32_f16(a2[mi], bg[ni], acc2[mi][ni], 0, 0, 0);
        }
        if (more) store_b(e, cur ^ 1);
        __syncthreads();
    }

    // transpose-bounce both outputs -> coalesced [B,512,128] fp16 (h-permuted rows), final scale
    const int n_l = t >> 2, qu = t & 3;
    const int nm = p64(n_l);
    #pragma unroll
    for (int mi = 0; mi < 4; mi++)
    #pragma unroll
    for (int r = 0; r < 4; r++) {
        int ml = wr * 64 + mi * 16 + fg * 4 + r;
        float fs = fin[0][ml];
        #pragma unroll
        for (int ni = 0; ni < 2; ni++)
            TT[(wc * 32 + ni * 16 + fr) * 136 + ml] = f2h(acc1[mi][ni][r] * fs);
    }
    __syncthreads();
    {
        short* dst = Y1T + ((size_t)b * 512 + n0 + nm) * 128 + qu * 32;
        #pragma unroll
        for (int j = 0; j < 4; j++)
            *(bf16x8*)(dst + j * 8) = *(const bf16x8*)&TT[n_l * 136 + qu * 32 + j * 8];
    }
    __syncthreads();
    #pragma unroll
    for (int mi = 0; mi < 4; mi++)
    #pragma unroll
    for (int r = 0; r < 4; r++) {
        int ml = wr * 64 + mi * 16 + fg * 4 + r;
        float fs = fin[1][ml];
        #pragma unroll
        for (int ni = 0; ni < 2; ni++)
            TT[(wc * 32 + ni * 16 + fr) * 136 + ml] = f2h(acc2[mi][ni][r] * fs);
    }
    __syncthreads();
    {
        short* dst = Y2T + ((size_t)b * 512 + n0 + nm) * 128 + qu * 32;
        #pragma unroll
        for (int j = 0; j < 4; j++)
            *(bf16x8*)(dst + j * 8) = *(const bf16x8*)&TT[n_l * 136 + qu * 32 + j * 8];
    }
}

// ---------------- epilogue GEMM (K=128, fp16), direct-global fragments, float4 fused output writes ----------------
template<bool WITHC>
__global__ __launch_bounds__(256)
void k_epi(const short* __restrict__ Pm, const short* __restrict__ BT1,
           const short* __restrict__ BT2, const short* __restrict__ C16,
           float* __restrict__ out)
{
    const int t = threadIdx.x;
    const int hb = (int)(blockIdx.x & 3);
    const int mb = (int)((blockIdx.x >> 2) & 7);
    const int b  = (int)(blockIdx.x >> 5);
    const int m0 = mb * 128, h0 = hb * 128;
    const int lane = t & 63;
    const int wr = (t >> 7) & 1, wc = (t >> 6) & 1;
    const int fr = lane & 15, fg = lane >> 4;
    f32x4 acc1[4][4] = {}, acc2[4][4] = {};
    const short* Abase  = Pm  + ((size_t)b * 1024 + m0) * 128;
    const short* B1base = BT1 + ((size_t)b * 512 + h0) * 128;
    const short* B2base = BT2 + ((size_t)b * 512 + h0) * 128;
    #pragma unroll
    for (int kk = 0; kk < 4; kk++) {
        const int k0 = kk * 32;
        f16x8 af[4], b1[4], b2[4];
        #pragma unroll
        for (int i = 0; i < 4; i++) {
            af[i] = *(const f16x8*)(Abase  + (size_t)(wr * 64 + i * 16 + fr) * 128 + k0 + fg * 8);
            b1[i] = *(const f16x8*)(B1base + (size_t)(wc * 64 + i * 16 + fr) * 128 + k0 + fg * 8);
            b2[i] = *(const f16x8*)(B2base + (size_t)(wc * 64 + i * 16 + fr) * 128 + k0 + fg * 8);
        }
        #pragma unroll
        for (int mi = 0; mi < 4; mi++)
        #pragma unroll
        for (int ni = 0; ni < 4; ni++) {
            acc1[mi][ni] = __builtin_amdgcn_mfma_f32_16x16x32_f16(af[mi], b1[ni], acc1[mi][ni], 0, 0, 0);
            acc2[mi][ni] = __builtin_amdgcn_mfma_f32_16x16x32_f16(af[mi], b2[ni], acc2[mi][ni], 0, 0, 0);
        }
    }
    const size_t crow_base = (size_t)b * 1024 + m0;
    const int colb = wc * 64 + fr * 4;       // logical column base (4 consecutive)
    #pragma unroll
    for (int mi = 0; mi < 4; mi++)
    #pragma unroll
    for (int r = 0; r < 4; r++) {
        int rowl = wr * 64 + mi * 16 + fg * 4 + r;
        size_t obase = (crow_base + rowl) * 3072 + h0 + colb;
        float4 av, bv;
        av.x = acc1[mi][0][r]; av.y = acc1[mi][1][r]; av.z = acc1[mi][2][r]; av.w = acc1[mi][3][r];
        bv.x = acc2[mi][0][r]; bv.y = acc2[mi][1][r]; bv.z = acc2[mi][2][r]; bv.w = acc2[mi][3][r];
        if (WITHC) {
            f16x4 cv4 = *(const f16x4*)(C16 + (crow_base + rowl) * 512 + h0 + colb);
            float4 cv;
            cv.x = (float)cv4[0]; cv.y = (float)cv4[1]; cv.z = (float)cv4[2]; cv.w = (float)cv4[3];
            *(float4*)(out + obase) = cv;
            *(float4*)(out + obase + 512) = av;
            float4 ca; ca.x = cv.x * av.x; ca.y = cv.y * av.y; ca.z = cv.z * av.z; ca.w = cv.w * av.w;
            *(float4*)(out + obase + 1024) = ca;
            float4 cb; cb.x = cv.x * bv.x; cb.y = cv.y * bv.y; cb.z = cv.z * bv.z; cb.w = cv.w * bv.w;
            *(float4*)(out + obase + 1536) = cb;
        } else {
            *(float4*)(out + obase + 2048) = bv;
            *(float4*)(out + obase + 2560) = av;
        }
    }
}

// ---------------- host launcher ----------------
extern "C" void kernel_launch(void* const* d_in, const int* in_sizes, int n_in,
                              void* d_out, int out_size, void* d_ws, size_t ws_size,
                              hipStream_t stream)
{
    const float* c     = (const float*)d_in[0];
    const float* q     = (const float*)d_in[1];
    const int*   cmask = (const int*)d_in[2];
    const int*   qmask = (const int*)d_in[3];
    const float* cwv   = (const float*)d_in[4];
    const float* qwv   = (const float*)d_in[5];
    const float* cqw   = (const float*)d_in[6];
    const float* bias  = (const float*)d_in[7];
    const float* W1    = (const float*)d_in[8];
    const float* b1    = (const float*)d_in[9];
    const float* W2    = (const float*)d_in[10];
    const float* b2    = (const float*)d_in[11];
    float* out = (float*)d_out;

    char* ws = (char*)d_ws;
    size_t off = 0;
    auto alloc = [&](size_t bytes) -> char* {
        char* p = ws + off;
        off = (off + bytes + 255) & ~(size_t)255;
        return p;
    };
    short* w1th = (short*)alloc(512 * 512 * 2);
    short* w1tl = (short*)alloc(512 * 512 * 2);
    short* w2th = (short*)alloc(512 * 512 * 2);
    short* w2tl = (short*)alloc(512 * 512 * 2);
    float* s1p  = (float*)alloc(64 * 4 * 128 * 4);
    short* q_cq = (short*)alloc((size_t)64 * 128 * 512 * 2);
    short* qT   = (short*)alloc((size_t)64 * 512 * 128 * 2);
    float* z1   = (float*)alloc((size_t)8192 * 512 * 4);     // layer-1 act; reused for binT/bcoT
    short* qp_f = (short*)alloc((size_t)8192 * 512 * 2);     // fp16 qp
    short* qpT  = (short*)alloc((size_t)64 * 512 * 128 * 2);
    short* c16  = (short*)alloc((size_t)64 * 1024 * 512 * 2);  // fp16 c (exported by k_att_dual)
    float2* colpartS = (float2*)alloc((size_t)64 * 8 * 128 * 8);
    float2* colpartC = (float2*)alloc((size_t)64 * 8 * 128 * 8);
    short* s1s  = (short*)alloc((size_t)64 * 1024 * 128 * 2);
    short* s2sT = (short*)alloc((size_t)64 * 128 * 1024 * 2);  // raw per-chunk exp (fp16)
    short* sc1  = (short*)alloc((size_t)64 * 1024 * 128 * 2);
    short* sc2T = (short*)alloc((size_t)64 * 128 * 1024 * 2);  // raw per-chunk exp (fp16)
    short* binT = (short*)z1;
    short* bcoT = ((short*)z1) + (size_t)64 * 512 * 128;

    k_prep_w<<<2048, 256, 0, stream>>>(W1, W2, w1th, w1tl, w2th, w2tl);
    k_prep_q<<<256, 256, 0, stream>>>(q, qwv, cqw, q_cq, qT, s1p);
    k_linear<false><<<256, 256, 0, stream>>>(q, w1th, w1tl, b1, z1, nullptr, nullptr);
    k_linear<true><<<256, 256, 0, stream>>>(z1, w2th, w2tl, b2, nullptr, qp_f, qpT);

    // merged logits pipelines: one c read, both GEMMs, c16 export
    k_att_dual<<<512, 256, 0, stream>>>(
        c, q_cq, qp_f, cwv, s1p, bias, qmask, cmask, c16,
        s1s, s2sT, colpartS, sc1, sc2T, colpartC);

    // fused dual K=1024 GEMM (fp16 c16 input) with inline column-softmax normalization
    k_kgemm2<<<512, 256, 0, stream>>>(s2sT, sc2T, c16, colpartS, colpartC, binT, bcoT);

    // fused output epilogues (fp16 MFMA, float4 stores via h-permutation)
    k_epi<true><<<2048, 256, 0, stream>>>(s1s, qT, binT, c16, out);
    k_epi<false><<<2048, 256, 0, stream>>>(sc1, qpT, bcoT, nullptr, out);
}